// Round 1
// baseline (3655.885 us; speedup 1.0000x reference)
//
#include <hip/hip_runtime.h>

namespace {
constexpr int kT = 1024, kD = 2048, kH = 16, kNOPE = 128, kROPE = 64, kVD = 128, kQKD = 192;
constexpr int kQL = 768, kKVL = 512, kIH = 32, kID = 128, kTOPK = 256, kE = 8, kF = 1024;
constexpr int kQKV_N = kQL + kKVL + kROPE; // 1344
}

// ---------------- device helpers ----------------
__device__ __forceinline__ float wsum(float v) {
#pragma unroll
  for (int o = 32; o; o >>= 1) v += __shfl_xor(v, o, 64);
  return v;
}
__device__ __forceinline__ float wmax64(float v) {
#pragma unroll
  for (int o = 32; o; o >>= 1) v = fmaxf(v, __shfl_xor(v, o, 64));
  return v;
}
__device__ __forceinline__ int wsum_i(int v) {
#pragma unroll
  for (int o = 32; o; o >>= 1) v += __shfl_xor(v, o, 64);
  return v;
}
__device__ __forceinline__ float bsum256(float v, float* red) {
  v = wsum(v);
  if ((threadIdx.x & 63) == 0) red[threadIdx.x >> 6] = v;
  __syncthreads();
  float t = red[0] + red[1] + red[2] + red[3];
  __syncthreads();
  return t;
}
__device__ __forceinline__ unsigned sortkey(float f) {
  unsigned b = __float_as_uint(f);
  return (b & 0x80000000u) ? ~b : (b | 0x80000000u);
}
// smallest power of two >= z (z > 0, normal)
__device__ __forceinline__ float pow2ceil(float z) {
  unsigned b = __float_as_uint(z);
  if ((b & 0x7FFFFFu) == 0) return z;
  return __uint_as_float((((b >> 23) & 0xFFu) + 1u) << 23);
}
// round-to-nearest-even quantization to e4m3fn grid; |x| <= 448 assumed
__device__ __forceinline__ float fp8q(float x) {
  float ax = fabsf(x);
  float q;
  if (ax < 0.015625f) { // subnormal range: quantum 2^-9
    q = rintf(ax * 512.0f) * 0.001953125f;
  } else {
    unsigned b = __float_as_uint(ax);
    int e = (int)((b >> 23) & 0xFF) - 127;       // ax in [2^e, 2^{e+1})
    float quant = __uint_as_float((unsigned)(e - 3 + 127) << 23);   // 2^{e-3}
    float rq    = __uint_as_float((unsigned)(127 - (e - 3)) << 23); // 2^{3-e}
    q = rintf(ax * rq) * quant;
  }
  return copysignf(q, x);
}

// ---------------- kernels ----------------

// resid = h + r ; out = rmsnorm(resid, w)
__global__ __launch_bounds__(256) void k_add_rms(const float* __restrict__ h, const float* __restrict__ r,
                                                 const float* __restrict__ w, float* __restrict__ resid,
                                                 float* __restrict__ out) {
  __shared__ float row[kD];
  __shared__ float red[4];
  int t = blockIdx.x;
  size_t base = (size_t)t * kD;
  float ss = 0.f;
  for (int c = threadIdx.x; c < kD; c += 256) {
    float v = h[base + c] + r[base + c];
    row[c] = v; resid[base + c] = v; ss += v * v;
  }
  float tot = bsum256(ss, red);
  float inv = 1.0f / sqrtf(tot * (1.0f / kD) + 1e-6f);
  for (int c = threadIdx.x; c < kD; c += 256) out[base + c] = row[c] * inv * w[c];
}

// out[t, 0:cols] = rmsnorm(in[t*stride+off : +cols], w)
__global__ __launch_bounds__(256) void k_rms_rows(const float* __restrict__ in, int stride, int off,
                                                  const float* __restrict__ w, float* __restrict__ out, int cols) {
  __shared__ float row[kD];
  __shared__ float red[4];
  int t = blockIdx.x;
  const float* x = in + (size_t)t * stride + off;
  float ss = 0.f;
  for (int c = threadIdx.x; c < cols; c += 256) { float v = x[c]; row[c] = v; ss += v * v; }
  float tot = bsum256(ss, red);
  float inv = 1.0f / sqrtf(tot / (float)cols + 1e-6f);
  for (int c = threadIdx.x; c < cols; c += 256) out[(size_t)t * cols + c] = row[c] * inv * w[c];
}

// C[M,N] = A[M,K] @ B[K,N] (+addend). K % 16 == 0 required.
__global__ __launch_bounds__(256) void k_gemm(const float* __restrict__ A, const float* __restrict__ B,
                                              float* __restrict__ C, int M, int N, int K,
                                              const float* __restrict__ addend) {
  __shared__ float As[16][68];
  __shared__ float Bs[16][68];
  int bm = blockIdx.y * 64, bn = blockIdx.x * 64;
  int tid = threadIdx.x, tx = tid & 15, ty = tid >> 4;
  int tx4 = tx * 4, ty4 = ty * 4;
  int ar = tid >> 2, ak = (tid & 3) << 2;
  int brk = tid >> 4, bn0 = (tid & 15) << 2;
  float acc[4][4] = {};
  for (int k0 = 0; k0 < K; k0 += 16) {
    {
      int gm = bm + ar;
      if (gm < M) {
        const float4 a4 = *(const float4*)&A[(size_t)gm * K + k0 + ak];
        As[ak][ar] = a4.x; As[ak + 1][ar] = a4.y; As[ak + 2][ar] = a4.z; As[ak + 3][ar] = a4.w;
      } else {
        As[ak][ar] = 0.f; As[ak + 1][ar] = 0.f; As[ak + 2][ar] = 0.f; As[ak + 3][ar] = 0.f;
      }
    }
    {
      int gk = k0 + brk;
      int gn = bn + bn0;
      if (gn + 3 < N) {
        const float4 b4 = *(const float4*)&B[(size_t)gk * N + gn];
        Bs[brk][bn0] = b4.x; Bs[brk][bn0 + 1] = b4.y; Bs[brk][bn0 + 2] = b4.z; Bs[brk][bn0 + 3] = b4.w;
      } else {
#pragma unroll
        for (int i = 0; i < 4; i++) Bs[brk][bn0 + i] = (gn + i < N) ? B[(size_t)gk * N + gn + i] : 0.f;
      }
    }
    __syncthreads();
#pragma unroll
    for (int kk = 0; kk < 16; kk++) {
      float a0 = As[kk][ty4], a1 = As[kk][ty4 + 1], a2 = As[kk][ty4 + 2], a3 = As[kk][ty4 + 3];
      float b0 = Bs[kk][tx4], b1 = Bs[kk][tx4 + 1], b2 = Bs[kk][tx4 + 2], b3 = Bs[kk][tx4 + 3];
      acc[0][0] += a0 * b0; acc[0][1] += a0 * b1; acc[0][2] += a0 * b2; acc[0][3] += a0 * b3;
      acc[1][0] += a1 * b0; acc[1][1] += a1 * b1; acc[1][2] += a1 * b2; acc[1][3] += a1 * b3;
      acc[2][0] += a2 * b0; acc[2][1] += a2 * b1; acc[2][2] += a2 * b2; acc[2][3] += a2 * b3;
      acc[3][0] += a3 * b0; acc[3][1] += a3 * b1; acc[3][2] += a3 * b2; acc[3][3] += a3 * b3;
    }
    __syncthreads();
  }
#pragma unroll
  for (int i = 0; i < 4; i++) {
    int gm = bm + ty4 + i;
    if (gm >= M) continue;
#pragma unroll
    for (int j = 0; j < 4; j++) {
      int gn = bn + tx4 + j;
      if (gn >= N) continue;
      float v = acc[i][j];
      if (addend) v += addend[(size_t)gm * N + gn];
      C[(size_t)gm * N + gn] = v;
    }
  }
}

// rope on q[..., 128:192] in place
__global__ __launch_bounds__(256) void k_rope_q(float* __restrict__ q, const int* __restrict__ pos) {
  int t = blockIdx.x;
  float p = (float)pos[t];
  for (int idx = threadIdx.x; idx < kH * 32; idx += 256) {
    int h = idx >> 5, j = idx & 31;
    float invf = 1.0f / powf(10000.0f, (float)j * 0.03125f);
    float ang = p * invf; float s, c; sincosf(ang, &s, &c);
    size_t base = ((size_t)t * kH + h) * kQKD + kNOPE + 2 * j;
    float x1 = q[base], x2 = q[base + 1];
    q[base] = x1 * c - x2 * s;
    q[base + 1] = x2 * c + x1 * s;
  }
}

// rope on iq[..., 0:64] in place
__global__ __launch_bounds__(256) void k_rope_iq(float* __restrict__ iq, const int* __restrict__ pos) {
  int t = blockIdx.x;
  float p = (float)pos[t];
  for (int idx = threadIdx.x; idx < kIH * 32; idx += 256) {
    int h = idx >> 5, j = idx & 31;
    float invf = 1.0f / powf(10000.0f, (float)j * 0.03125f);
    float ang = p * invf; float s, c; sincosf(ang, &s, &c);
    size_t base = ((size_t)t * kIH + h) * kID + 2 * j;
    float x1 = iq[base], x2 = iq[base + 1];
    iq[base] = x1 * c - x2 * s;
    iq[base + 1] = x2 * c + x1 * s;
  }
}

// k_pe = rope(qkv[:, 1280:1344])
__global__ __launch_bounds__(64) void k_rope_kpe(const float* __restrict__ qkv, const int* __restrict__ pos,
                                                 float* __restrict__ kpe) {
  int t = blockIdx.x; int j = threadIdx.x;
  if (j >= 32) return;
  float p = (float)pos[t];
  float invf = 1.0f / powf(10000.0f, (float)j * 0.03125f);
  float ang = p * invf; float s, c; sincosf(ang, &s, &c);
  const float* src = qkv + (size_t)t * kQKV_N + kQL + kKVL;
  float x1 = src[2 * j], x2 = src[2 * j + 1];
  kpe[(size_t)t * 64 + 2 * j] = x1 * c - x2 * s;
  kpe[(size_t)t * 64 + 2 * j + 1] = x2 * c + x1 * s;
}

// per-row (128 elems) fp8 quant in place, store scale. one wave per row.
__global__ __launch_bounds__(64) void k_quant_rows(float* __restrict__ x, float* __restrict__ scales) {
  int row = blockIdx.x;
  float* p = x + (size_t)row * kID;
  int l = threadIdx.x;
  float v0 = p[2 * l], v1 = p[2 * l + 1];
  float am = wmax64(fmaxf(fabsf(v0), fabsf(v1)));
  float scale = pow2ceil(fmaxf(am / 448.0f, 1e-10f));
  float inv = 1.0f / scale;
  p[2 * l]     = fp8q(fminf(fmaxf(v0 * inv, -448.f), 448.f));
  p[2 * l + 1] = fp8q(fminf(fmaxf(v1 * inv, -448.f), 448.f));
  if (l == 0) scales[row] = scale;
}

// ik: layernorm -> rope(first 64) -> fp8 quant. one wave per row.
__global__ __launch_bounds__(64) void k_ik_process(const float* __restrict__ raw, const float* __restrict__ w,
                                                   const float* __restrict__ b, const int* __restrict__ pos,
                                                   float* __restrict__ outq, float* __restrict__ scales) {
  int t = blockIdx.x; int l = threadIdx.x;
  const float* x = raw + (size_t)t * kID;
  float x0 = x[2 * l], x1 = x[2 * l + 1];
  float mean = wsum(x0 + x1) * (1.0f / 128.0f);
  float d0 = x0 - mean, d1 = x1 - mean;
  float var = wsum(d0 * d0 + d1 * d1) * (1.0f / 128.0f);
  float inv = 1.0f / sqrtf(var + 1e-6f);
  float y0 = d0 * inv * w[2 * l] + b[2 * l];
  float y1 = d1 * inv * w[2 * l + 1] + b[2 * l + 1];
  if (l < 32) {
    float p = (float)pos[t];
    float invf = 1.0f / powf(10000.0f, (float)l * 0.03125f);
    float ang = p * invf; float sn, cs; sincosf(ang, &sn, &cs);
    float r0 = y0 * cs - y1 * sn, r1 = y1 * cs + y0 * sn;
    y0 = r0; y1 = r1;
  }
  float am = wmax64(fmaxf(fabsf(y0), fabsf(y1)));
  float scale = pow2ceil(fmaxf(am / 448.0f, 1e-10f));
  float is = 1.0f / scale;
  outq[(size_t)t * kID + 2 * l]     = fp8q(fminf(fmaxf(y0 * is, -448.f), 448.f));
  outq[(size_t)t * kID + 2 * l + 1] = fp8q(fminf(fmaxf(y1 * is, -448.f), 448.f));
  if (l == 0) scales[t] = scale;
}

__global__ __launch_bounds__(256) void k_iw(const float* __restrict__ raw, const float* __restrict__ sc,
                                            float* __restrict__ out) {
  int i = blockIdx.x * 256 + threadIdx.x;
  if (i < kT * kIH) out[i] = raw[i] * sc[i] * 0.08838834764831845f * 0.17677669529663687f;
}

// scores[t,s] = sum_h iw[t,h] * relu( (iq[t,h,:].ik[s,:]) * ik_scale[s] )   for s<=t
__global__ __launch_bounds__(256) void k_scores(const float* __restrict__ iq, const float* __restrict__ ik,
                                                const float* __restrict__ iksc, const float* __restrict__ iw,
                                                float* __restrict__ scores) {
  __shared__ __align__(16) float iqs[kIH * kID];
  __shared__ float iws[kIH];
  int t = blockIdx.x;
  for (int i = threadIdx.x; i < kIH * kID; i += 256) iqs[i] = iq[(size_t)t * kIH * kID + i];
  if (threadIdx.x < kIH) iws[threadIdx.x] = iw[t * kIH + threadIdx.x];
  __syncthreads();
  for (int s = threadIdx.x; s <= t; s += 256) {
    float acc[kIH];
#pragma unroll
    for (int h = 0; h < kIH; h++) acc[h] = 0.f;
    const float4* kr = (const float4*)(ik + (size_t)s * kID);
    for (int d4 = 0; d4 < kID / 4; d4++) {
      float4 kv4 = kr[d4];
#pragma unroll
      for (int h = 0; h < kIH; h++) {
        const float4 q4 = *(const float4*)&iqs[h * kID + d4 * 4];
        acc[h] += q4.x * kv4.x + q4.y * kv4.y + q4.z * kv4.z + q4.w * kv4.w;
      }
    }
    float scv = iksc[s];
    float tot = 0.f;
#pragma unroll
    for (int h = 0; h < kIH; h++) tot += iws[h] * fmaxf(acc[h] * scv, 0.f);
    scores[(size_t)t * kT + s] = tot;
  }
}

// exact top-256 (lax.top_k tie semantics: ties by lowest index) -> mask bytes
__global__ __launch_bounds__(64) void k_topk(const float* __restrict__ scores, unsigned char* __restrict__ mask) {
  int t = blockIdx.x; int l = threadIdx.x;
  unsigned char* mrow = mask + (size_t)t * kT;
  if (t < kTOPK) {
    for (int s = l; s < kT; s += 64) mrow[s] = (s <= t) ? 1 : 0;
    return;
  }
  unsigned key[16];
  const float* srow = scores + (size_t)t * kT;
#pragma unroll
  for (int i = 0; i < 16; i++) {
    int s = l * 16 + i;
    key[i] = (s <= t) ? sortkey(srow[s]) : 0u;
  }
  unsigned prefix = 0; int remaining = kTOPK;
  for (int bit = 31; bit >= 0; bit--) {
    unsigned himask = 0xFFFFFFFFu << bit;
    unsigned cmp = prefix | (1u << bit);
    int c = 0;
#pragma unroll
    for (int i = 0; i < 16; i++) c += ((key[i] & himask) == cmp) ? 1 : 0;
    c = wsum_i(c);
    if (c >= remaining) prefix = cmp; else remaining -= c;
  }
  int ceq = 0, cgt = 0;
#pragma unroll
  for (int i = 0; i < 16; i++) { ceq += (key[i] == prefix) ? 1 : 0; cgt += (key[i] > prefix) ? 1 : 0; }
  int v = ceq;
#pragma unroll
  for (int o = 1; o < 64; o <<= 1) { int u = __shfl_up(v, o, 64); if (l >= o) v += u; }
  int rank = v - ceq;
  int need = kTOPK - wsum_i(cgt);
#pragma unroll
  for (int i = 0; i < 16; i++) {
    int s = l * 16 + i;
    unsigned char sel;
    if (key[i] > prefix) sel = 1;
    else if (key[i] == prefix) { sel = (rank < need) ? 1 : 0; rank++; }
    else sel = 0;
    mrow[s] = sel;
  }
}

// fused attention: one block = (head, 8 query rows)
__global__ __launch_bounds__(256) void k_attn(const float* __restrict__ q, const float* __restrict__ kv,
                                              const float* __restrict__ kpe, const unsigned char* __restrict__ mask,
                                              float* __restrict__ o) {
  __shared__ float att[8][kT];                       // 32 KB
  __shared__ __align__(16) float kq[32 * 196 + 8 * 196]; // 31360 B (k chunk + q tile; aliased as v chunk)
  float* qs = kq + 32 * 196;
  int h = blockIdx.y;
  int t0 = blockIdx.x * 8;
  int tid = threadIdx.x;
  int t_max = t0 + 7;
  for (int idx = tid; idx < 8 * 192; idx += 256) {
    int tq = idx / 192, d = idx - tq * 192;
    qs[tq * 196 + d] = q[((size_t)(t0 + tq) * kH + h) * kQKD + d];
  }
  __syncthreads();
  int tq = tid >> 5, sl = tid & 31;
  int t_row = t0 + tq;
  const unsigned char* mrow = mask + (size_t)t_row * kT;
  int nch = (t_max >> 5) + 1;
  for (int ch = 0; ch < nch; ch++) {
    int sc = ch << 5;
    for (int idx = tid; idx < 32 * 192; idx += 256) {
      int sr = idx / 192, d = idx - sr * 192;
      int s = sc + sr;
      float v = 0.f;
      if (s < kT) v = (d < 128) ? kv[((size_t)s * kH + h) * 256 + d] : kpe[(size_t)s * 64 + (d - 128)];
      kq[sr * 196 + d] = v;
    }
    __syncthreads();
    int s = sc + sl;
    if (s <= t_max) {
      float a = -1e30f;
      if (mrow[s]) {
        float accd = 0.f;
        const float4* qv = (const float4*)(qs + tq * 196);
        const float4* kr = (const float4*)(kq + sl * 196);
#pragma unroll
        for (int d4 = 0; d4 < 48; d4++) {
          float4 x = qv[d4], y = kr[d4];
          accd += x.x * y.x + x.y * y.y + x.z * y.z + x.w * y.w;
        }
        a = accd * 0.07216878364870323f;
      }
      att[tq][s] = a;
    }
    __syncthreads();
  }
  float m = -1e30f;
  for (int s = sl; s <= t_max; s += 32) m = fmaxf(m, att[tq][s]);
#pragma unroll
  for (int o2 = 16; o2; o2 >>= 1) m = fmaxf(m, __shfl_xor(m, o2, 32));
  float lsum = 0.f;
  for (int s = sl; s <= t_max; s += 32) { float p = expf(att[tq][s] - m); att[tq][s] = p; lsum += p; }
#pragma unroll
  for (int o2 = 16; o2; o2 >>= 1) lsum += __shfl_xor(lsum, o2, 32);
  float inv = 1.0f / lsum;
  __syncthreads();
  float oa0 = 0, oa1 = 0, oa2 = 0, oa3 = 0;
  float* vb = kq; // [32][128]
  for (int ch = 0; ch < nch; ch++) {
    int sc = ch << 5;
    for (int idx = tid; idx < 32 * 128; idx += 256) {
      int sr = idx >> 7, d = idx & 127;
      int s = sc + sr;
      vb[sr * 128 + d] = (s < kT) ? kv[((size_t)s * kH + h) * 256 + 128 + d] : 0.f;
    }
    __syncthreads();
    int smax = t_max - sc; if (smax > 31) smax = 31;
    for (int j = 0; j <= smax; j++) {
      float p = att[tq][sc + j];
      const float4 v4 = *(const float4*)&vb[j * 128 + sl * 4];
      oa0 += p * v4.x; oa1 += p * v4.y; oa2 += p * v4.z; oa3 += p * v4.w;
    }
    __syncthreads();
  }
  float4 res; res.x = oa0 * inv; res.y = oa1 * inv; res.z = oa2 * inv; res.w = oa3 * inv;
  *(float4*)&o[((size_t)t_row * kH + h) * kVD + sl * 4] = res;
}

// gate = sigmoid(hs2 @ w_gate), top2, append to per-expert token lists
__global__ __launch_bounds__(64) void k_route(const float* __restrict__ hs2, const float* __restrict__ wg,
                                              int* __restrict__ cnt, int* __restrict__ toki,
                                              float* __restrict__ tokw) {
  int t = blockIdx.x; int l = threadIdx.x;
  float acc[8] = {};
  for (int d = l; d < kD; d += 64) {
    float hv = hs2[(size_t)t * kD + d];
    const float* wr = wg + (size_t)d * 8;
#pragma unroll
    for (int e = 0; e < 8; e++) acc[e] += hv * wr[e];
  }
#pragma unroll
  for (int e = 0; e < 8; e++) acc[e] = wsum(acc[e]);
  if (l == 0) {
    float g[8];
#pragma unroll
    for (int e = 0; e < 8; e++) g[e] = 1.0f / (1.0f + expf(-acc[e]));
    int i0 = 0;
    for (int e = 1; e < 8; e++) if (g[e] > g[i0]) i0 = e;
    int i1 = (i0 == 0) ? 1 : 0;
    for (int e = 0; e < 8; e++) if (e != i0 && g[e] > g[i1]) i1 = e;
    float ssum = g[i0] + g[i1];
    float w0 = g[i0] / ssum * 2.5f, w1 = g[i1] / ssum * 2.5f;
    int s0 = atomicAdd(&cnt[i0], 1); toki[i0 * kT + s0] = t; tokw[i0 * kT + s0] = w0;
    int s1 = atomicAdd(&cnt[i1], 1); toki[i1 * kT + s1] = t; tokw[i1 * kT + s1] = w1;
  }
}

__global__ __launch_bounds__(256) void k_smid(float* __restrict__ g, const float* __restrict__ u, int n) {
  int i = blockIdx.x * 256 + threadIdx.x;
  if (i < n) { float x = g[i]; g[i] = x * (1.0f / (1.0f + expf(-x))) * u[i]; }
}

// gathered dual GEMM: hmid[e, i, f] = silu(hs2[tok] @ wg[e]) * (hs2[tok] @ wu[e])
__global__ __launch_bounds__(256) void k_moe_gu(const float* __restrict__ hs2, const float* __restrict__ wg,
                                                const float* __restrict__ wu, const int* __restrict__ toki,
                                                const int* __restrict__ cnt, float* __restrict__ hmid) {
  int e = blockIdx.z;
  int n = cnt[e];
  int bm = blockIdx.y * 64;
  if (bm >= n) return;
  int bn = blockIdx.x * 64;
  __shared__ float As[16][68];
  __shared__ float Bg[16][68];
  __shared__ float Bu[16][68];
  const float* gP = wg + (size_t)e * kD * kF;
  const float* uP = wu + (size_t)e * kD * kF;
  const int* tk = toki + e * kT;
  int tid = threadIdx.x, tx = tid & 15, ty = tid >> 4;
  int tx4 = tx * 4, ty4 = ty * 4;
  int ar = tid >> 2, ak = (tid & 3) << 2;
  int brk = tid >> 4, bn0 = (tid & 15) << 2;
  int arow = (bm + ar < n) ? tk[bm + ar] : -1;
  float ag[4][4] = {}, au[4][4] = {};
  for (int k0 = 0; k0 < kD; k0 += 16) {
    if (arow >= 0) {
      float4 a4 = *(const float4*)&hs2[(size_t)arow * kD + k0 + ak];
      As[ak][ar] = a4.x; As[ak + 1][ar] = a4.y; As[ak + 2][ar] = a4.z; As[ak + 3][ar] = a4.w;
    } else { As[ak][ar] = 0.f; As[ak + 1][ar] = 0.f; As[ak + 2][ar] = 0.f; As[ak + 3][ar] = 0.f; }
    {
      size_t boff = (size_t)(k0 + brk) * kF + bn + bn0;
      float4 g4 = *(const float4*)&gP[boff];
      float4 u4 = *(const float4*)&uP[boff];
      Bg[brk][bn0] = g4.x; Bg[brk][bn0 + 1] = g4.y; Bg[brk][bn0 + 2] = g4.z; Bg[brk][bn0 + 3] = g4.w;
      Bu[brk][bn0] = u4.x; Bu[brk][bn0 + 1] = u4.y; Bu[brk][bn0 + 2] = u4.z; Bu[brk][bn0 + 3] = u4.w;
    }
    __syncthreads();
#pragma unroll
    for (int kk = 0; kk < 16; kk++) {
      float a0 = As[kk][ty4], a1 = As[kk][ty4 + 1], a2 = As[kk][ty4 + 2], a3 = As[kk][ty4 + 3];
      float g0 = Bg[kk][tx4], g1 = Bg[kk][tx4 + 1], g2 = Bg[kk][tx4 + 2], g3 = Bg[kk][tx4 + 3];
      float u0 = Bu[kk][tx4], u1 = Bu[kk][tx4 + 1], u2 = Bu[kk][tx4 + 2], u3 = Bu[kk][tx4 + 3];
      ag[0][0] += a0 * g0; ag[0][1] += a0 * g1; ag[0][2] += a0 * g2; ag[0][3] += a0 * g3;
      ag[1][0] += a1 * g0; ag[1][1] += a1 * g1; ag[1][2] += a1 * g2; ag[1][3] += a1 * g3;
      ag[2][0] += a2 * g0; ag[2][1] += a2 * g1; ag[2][2] += a2 * g2; ag[2][3] += a2 * g3;
      ag[3][0] += a3 * g0; ag[3][1] += a3 * g1; ag[3][2] += a3 * g2; ag[3][3] += a3 * g3;
      au[0][0] += a0 * u0; au[0][1] += a0 * u1; au[0][2] += a0 * u2; au[0][3] += a0 * u3;
      au[1][0] += a1 * u0; au[1][1] += a1 * u1; au[1][2] += a1 * u2; au[1][3] += a1 * u3;
      au[2][0] += a2 * u0; au[2][1] += a2 * u1; au[2][2] += a2 * u2; au[2][3] += a2 * u3;
      au[3][0] += a3 * u0; au[3][1] += a3 * u1; au[3][2] += a3 * u2; au[3][3] += a3 * u3;
    }
    __syncthreads();
  }
#pragma unroll
  for (int i = 0; i < 4; i++) {
    int gm = bm + ty4 + i;
    if (gm >= n) continue;
    size_t obase = (size_t)e * kT * kF + (size_t)gm * kF + bn;
#pragma unroll
    for (int j = 0; j < 4; j++) {
      float gv = ag[i][j], uv = au[i][j];
      hmid[obase + tx4 + j] = gv * (1.0f / (1.0f + expf(-gv))) * uv;
    }
  }
}

// routed += tok_w * (hmid[e] @ w_moe_down[e]) scattered by token id
__global__ __launch_bounds__(256) void k_moe_down(const float* __restrict__ hmid, const float* __restrict__ wd,
                                                  const int* __restrict__ toki, const float* __restrict__ tokw,
                                                  const int* __restrict__ cnt, float* __restrict__ out) {
  int e = blockIdx.z; int n = cnt[e];
  int bm = blockIdx.y * 64; if (bm >= n) return;
  int bn = blockIdx.x * 64;
  __shared__ float As[16][68];
  __shared__ float Bs[16][68];
  const float* A = hmid + (size_t)e * kT * kF;
  const float* B = wd + (size_t)e * kF * kD;
  int tid = threadIdx.x, tx = tid & 15, ty = tid >> 4;
  int tx4 = tx * 4, ty4 = ty * 4;
  int ar = tid >> 2, ak = (tid & 3) << 2;
  int brk = tid >> 4, bn0 = (tid & 15) << 2;
  float acc[4][4] = {};
  for (int k0 = 0; k0 < kF; k0 += 16) {
    if (bm + ar < n) {
      float4 a4 = *(const float4*)&A[(size_t)(bm + ar) * kF + k0 + ak];
      As[ak][ar] = a4.x; As[ak + 1][ar] = a4.y; As[ak + 2][ar] = a4.z; As[ak + 3][ar] = a4.w;
    } else { As[ak][ar] = 0.f; As[ak + 1][ar] = 0.f; As[ak + 2][ar] = 0.f; As[ak + 3][ar] = 0.f; }
    {
      float4 b4 = *(const float4*)&B[(size_t)(k0 + brk) * kD + bn + bn0];
      Bs[brk][bn0] = b4.x; Bs[brk][bn0 + 1] = b4.y; Bs[brk][bn0 + 2] = b4.z; Bs[brk][bn0 + 3] = b4.w;
    }
    __syncthreads();
#pragma unroll
    for (int kk = 0; kk < 16; kk++) {
      float a0 = As[kk][ty4], a1 = As[kk][ty4 + 1], a2 = As[kk][ty4 + 2], a3 = As[kk][ty4 + 3];
      float b0 = Bs[kk][tx4], b1 = Bs[kk][tx4 + 1], b2 = Bs[kk][tx4 + 2], b3 = Bs[kk][tx4 + 3];
      acc[0][0] += a0 * b0; acc[0][1] += a0 * b1; acc[0][2] += a0 * b2; acc[0][3] += a0 * b3;
      acc[1][0] += a1 * b0; acc[1][1] += a1 * b1; acc[1][2] += a1 * b2; acc[1][3] += a1 * b3;
      acc[2][0] += a2 * b0; acc[2][1] += a2 * b1; acc[2][2] += a2 * b2; acc[2][3] += a2 * b3;
      acc[3][0] += a3 * b0; acc[3][1] += a3 * b1; acc[3][2] += a3 * b2; acc[3][3] += a3 * b3;
    }
    __syncthreads();
  }
#pragma unroll
  for (int i = 0; i < 4; i++) {
    int gm = bm + ty4 + i;
    if (gm >= n) continue;
    int tt = toki[e * kT + gm]; float w = tokw[e * kT + gm];
#pragma unroll
    for (int j = 0; j < 4; j++) atomicAdd(&out[(size_t)tt * kD + bn + tx4 + j], w * acc[i][j]);
  }
}

// ---------------- launch ----------------
extern "C" void kernel_launch(void* const* d_in, const int* in_sizes, int n_in,
                              void* d_out, int out_size, void* d_ws, size_t ws_size,
                              hipStream_t stream) {
  (void)in_sizes; (void)n_in; (void)out_size; (void)ws_size;
  const int*   positions  = (const int*)d_in[0];
  const float* hidden     = (const float*)d_in[1];
  const float* residual   = (const float*)d_in[2];
  const float* input_ln_w = (const float*)d_in[3];
  const float* post_ln_w  = (const float*)d_in[4];
  const float* w_qkv_a    = (const float*)d_in[5];
  const float* q_a_ln_w   = (const float*)d_in[6];
  const float* w_q_b      = (const float*)d_in[7];
  const float* kv_a_ln_w  = (const float*)d_in[8];
  const float* w_kv_b     = (const float*)d_in[9];
  const float* w_o        = (const float*)d_in[10];
  const float* w_idx_q_b  = (const float*)d_in[11];
  const float* w_idx_k    = (const float*)d_in[12];
  const float* idx_k_ln_w = (const float*)d_in[13];
  const float* idx_k_ln_b = (const float*)d_in[14];
  const float* w_idx_w    = (const float*)d_in[15];
  const float* w_gate     = (const float*)d_in[16];
  const float* w_moe_gate = (const float*)d_in[17];
  const float* w_moe_up   = (const float*)d_in[18];
  const float* w_moe_down = (const float*)d_in[19];
  const float* w_sh_gate  = (const float*)d_in[20];
  const float* w_sh_up    = (const float*)d_in[21];
  const float* w_sh_down  = (const float*)d_in[22];

  float* out0 = (float*)d_out;
  float* out1 = out0 + (size_t)kT * kD;

  float* W = (float*)d_ws;
  size_t off = 0;
  auto alloc = [&](size_t nfl) { float* p = W + off; off += nfl; return p; };
  float* resid   = alloc((size_t)kT * kD);
  float* hs      = alloc((size_t)kT * kD);
  float* qkv     = alloc((size_t)kT * kQKV_N);
  float* q_c     = alloc((size_t)kT * kQL);
  float* kv_cn   = alloc((size_t)kT * kKVL);
  float* qb      = alloc((size_t)kT * kH * kQKD);
  float* kvb     = alloc((size_t)kT * kH * 256);
  float* iqb     = alloc((size_t)kT * kIH * kID);
  float* ikraw   = alloc((size_t)kT * kID);
  float* ikb     = alloc((size_t)kT * kID);
  float* iksc    = alloc(kT);
  float* iqsc    = alloc((size_t)kT * kIH);
  float* iwraw   = alloc((size_t)kT * kIH);
  float* iwb     = alloc((size_t)kT * kIH);
  float* kpe     = alloc((size_t)kT * kROPE);
  float* scoresb = alloc((size_t)kT * kT);
  unsigned char* maskb = (unsigned char*)alloc((size_t)kT * kT / 4);
  float* o_attn  = alloc((size_t)kT * kH * kVD);
  float* hs2     = alloc((size_t)kT * kD);
  float* sg      = alloc((size_t)kT * kF);
  float* su      = alloc((size_t)kT * kF);
  float* hmid    = alloc((size_t)kE * kT * kF);
  float* tokw    = alloc((size_t)kE * kT);
  int*   toki    = (int*)alloc((size_t)kE * kT);
  int*   cnt     = (int*)alloc(16);

  k_add_rms<<<kT, 256, 0, stream>>>(hidden, residual, input_ln_w, resid, hs);
  { dim3 g((kQKV_N + 63) / 64, kT / 64); k_gemm<<<g, 256, 0, stream>>>(hs, w_qkv_a, qkv, kT, kQKV_N, kD, nullptr); }
  k_rms_rows<<<kT, 256, 0, stream>>>(qkv, kQKV_N, 0, q_a_ln_w, q_c, kQL);
  k_rms_rows<<<kT, 256, 0, stream>>>(qkv, kQKV_N, kQL, kv_a_ln_w, kv_cn, kKVL);
  { dim3 g((kH * kQKD) / 64, kT / 64); k_gemm<<<g, 256, 0, stream>>>(q_c, w_q_b, qb, kT, kH * kQKD, kQL, nullptr); }
  { dim3 g((kIH * kID) / 64, kT / 64); k_gemm<<<g, 256, 0, stream>>>(q_c, w_idx_q_b, iqb, kT, kIH * kID, kQL, nullptr); }
  { dim3 g((kH * 256) / 64, kT / 64); k_gemm<<<g, 256, 0, stream>>>(kv_cn, w_kv_b, kvb, kT, kH * 256, kKVL, nullptr); }
  { dim3 g(2, kT / 64); k_gemm<<<g, 256, 0, stream>>>(hs, w_idx_k, ikraw, kT, kID, kD, nullptr); }
  { dim3 g(1, kT / 64); k_gemm<<<g, 256, 0, stream>>>(hs, w_idx_w, iwraw, kT, kIH, kD, nullptr); }
  k_rope_q<<<kT, 256, 0, stream>>>(qb, positions);
  k_rope_iq<<<kT, 256, 0, stream>>>(iqb, positions);
  k_rope_kpe<<<kT, 64, 0, stream>>>(qkv, positions, kpe);
  k_quant_rows<<<kT * kIH, 64, 0, stream>>>(iqb, iqsc);
  k_ik_process<<<kT, 64, 0, stream>>>(ikraw, idx_k_ln_w, idx_k_ln_b, positions, ikb, iksc);
  k_iw<<<(kT * kIH + 255) / 256, 256, 0, stream>>>(iwraw, iqsc, iwb);
  k_scores<<<kT, 256, 0, stream>>>(iqb, ikb, iksc, iwb, scoresb);
  k_topk<<<kT, 64, 0, stream>>>(scoresb, maskb);
  { dim3 g(kT / 8, kH); k_attn<<<g, 256, 0, stream>>>(qb, kvb, kpe, maskb, o_attn); }
  { dim3 g(kD / 64, kT / 64); k_gemm<<<g, 256, 0, stream>>>(o_attn, w_o, out1, kT, kD, kH * kVD, resid); }
  k_rms_rows<<<kT, 256, 0, stream>>>(out1, kD, 0, post_ln_w, hs2, kD);
  hipMemsetAsync(cnt, 0, 8 * sizeof(int), stream);
  k_route<<<kT, 64, 0, stream>>>(hs2, w_gate, cnt, toki, tokw);
  { dim3 g(kF / 64, kT / 64); k_gemm<<<g, 256, 0, stream>>>(hs2, w_sh_gate, sg, kT, kF, kD, nullptr); }
  { dim3 g(kF / 64, kT / 64); k_gemm<<<g, 256, 0, stream>>>(hs2, w_sh_up, su, kT, kF, kD, nullptr); }
  k_smid<<<(kT * kF + 255) / 256, 256, 0, stream>>>(sg, su, kT * kF);
  { dim3 g(kD / 64, kT / 64); k_gemm<<<g, 256, 0, stream>>>(sg, w_sh_down, out0, kT, kD, kF, nullptr); }
  { dim3 g(kF / 64, kT / 64, kE); k_moe_gu<<<g, 256, 0, stream>>>(hs2, w_moe_gate, w_moe_up, toki, cnt, hmid); }
  { dim3 g(kD / 64, kT / 64, kE); k_moe_down<<<g, 256, 0, stream>>>(hmid, w_moe_down, toki, tokw, cnt, out0); }
}

// Round 2
// 2875.094 us; speedup vs baseline: 1.2716x; 1.2716x over previous
//
#include <hip/hip_runtime.h>

namespace {
constexpr int kT = 1024, kD = 2048, kH = 16, kNOPE = 128, kROPE = 64, kVD = 128, kQKD = 192;
constexpr int kQL = 768, kKVL = 512, kIH = 32, kID = 128, kTOPK = 256, kE = 8, kF = 1024;
constexpr int kQKV_N = kQL + kKVL + kROPE; // 1344
}

typedef __attribute__((ext_vector_type(4))) float floatx4;
typedef __attribute__((ext_vector_type(8))) short short8;

// ---------------- device helpers ----------------
__device__ __forceinline__ float wsum(float v) {
#pragma unroll
  for (int o = 32; o; o >>= 1) v += __shfl_xor(v, o, 64);
  return v;
}
__device__ __forceinline__ float wmax64(float v) {
#pragma unroll
  for (int o = 32; o; o >>= 1) v = fmaxf(v, __shfl_xor(v, o, 64));
  return v;
}
__device__ __forceinline__ int wsum_i(int v) {
#pragma unroll
  for (int o = 32; o; o >>= 1) v += __shfl_xor(v, o, 64);
  return v;
}
__device__ __forceinline__ float bsum256(float v, float* red) {
  v = wsum(v);
  if ((threadIdx.x & 63) == 0) red[threadIdx.x >> 6] = v;
  __syncthreads();
  float t = red[0] + red[1] + red[2] + red[3];
  __syncthreads();
  return t;
}
__device__ __forceinline__ unsigned sortkey(float f) {
  unsigned b = __float_as_uint(f);
  return (b & 0x80000000u) ? ~b : (b | 0x80000000u);
}
__device__ __forceinline__ float pow2ceil(float z) {
  unsigned b = __float_as_uint(z);
  if ((b & 0x7FFFFFu) == 0) return z;
  return __uint_as_float((((b >> 23) & 0xFFu) + 1u) << 23);
}
__device__ __forceinline__ float fp8q(float x) {
  float ax = fabsf(x);
  float q;
  if (ax < 0.015625f) {
    q = rintf(ax * 512.0f) * 0.001953125f;
  } else {
    unsigned b = __float_as_uint(ax);
    int e = (int)((b >> 23) & 0xFF) - 127;
    float quant = __uint_as_float((unsigned)(e - 3 + 127) << 23);
    float rq    = __uint_as_float((unsigned)(127 - (e - 3)) << 23);
    q = rintf(ax * rq) * quant;
  }
  return copysignf(q, x);
}
// f32 -> bf16 RNE
__device__ __forceinline__ unsigned short f2bf(float x) {
  unsigned u = __float_as_uint(x);
  u += 0x7FFFu + ((u >> 16) & 1u);
  return (unsigned short)(u >> 16);
}

// ---------------- MFMA bf16 GEMM family ----------------
// 128x128 tile, 256 threads (4 waves, 2x2 quadrants of 64x64), BK=32.
// LDS layout: As[m][k] / Bs[n][k], row stride 40 bf16 (80 B) to break bank strides.

// C[M,N] = A[M,K]@B[K,N] (+addend). M%128==0, N%128==0, K%32==0.
__global__ __launch_bounds__(256) void k_gemm_bf16(const float* __restrict__ A, const float* __restrict__ B,
                                                   float* __restrict__ C, const float* __restrict__ addend,
                                                   int M, int N, int K) {
  __shared__ __align__(16) unsigned short As[128 * 40];
  __shared__ __align__(16) unsigned short Bs[128 * 40];
  int tid = threadIdx.x;
  int bm = blockIdx.y * 128, bn = blockIdx.x * 128;
  int wave = tid >> 6, lane = tid & 63;
  int wy = (wave >> 1) * 64, wx = (wave & 1) * 64;
  int lm = lane & 15, lk = lane >> 4;
  floatx4 acc[4][4] = {};
  for (int k0 = 0; k0 < K; k0 += 32) {
#pragma unroll
    for (int i = 0; i < 4; i++) {
      int lin = tid + i * 256;
      int m = lin >> 3, kq = (lin & 7) << 2;
      const float4 a4 = *(const float4*)&A[(size_t)(bm + m) * K + k0 + kq];
      ushort4 p; p.x = f2bf(a4.x); p.y = f2bf(a4.y); p.z = f2bf(a4.z); p.w = f2bf(a4.w);
      *(ushort4*)&As[m * 40 + kq] = p;
    }
#pragma unroll
    for (int i = 0; i < 2; i++) {
      int u = tid + i * 256;
      int k2 = u & 15, nq = (u >> 4) << 2;
      const float4 b0 = *(const float4*)&B[(size_t)(k0 + 2 * k2) * N + bn + nq];
      const float4 b1 = *(const float4*)&B[(size_t)(k0 + 2 * k2 + 1) * N + bn + nq];
      *(unsigned*)&Bs[(nq + 0) * 40 + 2 * k2] = (unsigned)f2bf(b0.x) | ((unsigned)f2bf(b1.x) << 16);
      *(unsigned*)&Bs[(nq + 1) * 40 + 2 * k2] = (unsigned)f2bf(b0.y) | ((unsigned)f2bf(b1.y) << 16);
      *(unsigned*)&Bs[(nq + 2) * 40 + 2 * k2] = (unsigned)f2bf(b0.z) | ((unsigned)f2bf(b1.z) << 16);
      *(unsigned*)&Bs[(nq + 3) * 40 + 2 * k2] = (unsigned)f2bf(b0.w) | ((unsigned)f2bf(b1.w) << 16);
    }
    __syncthreads();
    short8 af[4], bfr[4];
#pragma unroll
    for (int mt = 0; mt < 4; mt++) af[mt] = *(short8*)&As[(wy + mt * 16 + lm) * 40 + lk * 8];
#pragma unroll
    for (int nt = 0; nt < 4; nt++) bfr[nt] = *(short8*)&Bs[(wx + nt * 16 + lm) * 40 + lk * 8];
#pragma unroll
    for (int mt = 0; mt < 4; mt++)
#pragma unroll
      for (int nt = 0; nt < 4; nt++)
        acc[mt][nt] = __builtin_amdgcn_mfma_f32_16x16x32_bf16(af[mt], bfr[nt], acc[mt][nt], 0, 0, 0);
    __syncthreads();
  }
#pragma unroll
  for (int mt = 0; mt < 4; mt++) {
#pragma unroll
    for (int nt = 0; nt < 4; nt++) {
#pragma unroll
      for (int r = 0; r < 4; r++) {
        int m = bm + wy + mt * 16 + lk * 4 + r;
        int n = bn + wx + nt * 16 + lm;
        float v = acc[mt][nt][r];
        if (addend) v += addend[(size_t)m * N + n];
        C[(size_t)m * N + n] = v;
      }
    }
  }
}

// dual-B (gate+up) with fused silu(g)*u epilogue; optional row gather via toki.
// out rows live at out + e*kT*N (compact per expert). N%128==0, K%32==0.
__global__ __launch_bounds__(256) void k_dual_bf16(const float* __restrict__ A, const float* __restrict__ Bg,
                                                   const float* __restrict__ Bu, float* __restrict__ out,
                                                   const int* __restrict__ toki, const int* __restrict__ cnt,
                                                   int M, int N, int K) {
  int e = blockIdx.z;
  int n_rows = toki ? cnt[e] : M;
  int bm = blockIdx.y * 128;
  if (bm >= n_rows) return;
  int bn = blockIdx.x * 128;
  const int* tk = toki ? (toki + e * kT) : nullptr;
  const float* gP = Bg + (size_t)e * K * N;
  const float* uP = Bu + (size_t)e * K * N;
  float* oP = out + (size_t)e * kT * N;
  __shared__ __align__(16) unsigned short As[128 * 40];
  __shared__ __align__(16) unsigned short Gs[128 * 40];
  __shared__ __align__(16) unsigned short Us[128 * 40];
  int tid = threadIdx.x;
  int wave = tid >> 6, lane = tid & 63;
  int wy = (wave >> 1) * 64, wx = (wave & 1) * 64;
  int lm = lane & 15, lk = lane >> 4;
  // per-thread A-row gather indices (4 staging rows)
  int arow[4];
#pragma unroll
  for (int i = 0; i < 4; i++) {
    int lin = tid + i * 256;
    int m = lin >> 3;
    int gm = bm + m;
    arow[i] = (gm < n_rows) ? (tk ? tk[gm] : gm) : -1;
  }
  floatx4 ag[4][4] = {}, au[4][4] = {};
  for (int k0 = 0; k0 < K; k0 += 32) {
#pragma unroll
    for (int i = 0; i < 4; i++) {
      int lin = tid + i * 256;
      int m = lin >> 3, kq = (lin & 7) << 2;
      ushort4 p;
      if (arow[i] >= 0) {
        const float4 a4 = *(const float4*)&A[(size_t)arow[i] * K + k0 + kq];
        p.x = f2bf(a4.x); p.y = f2bf(a4.y); p.z = f2bf(a4.z); p.w = f2bf(a4.w);
      } else { p.x = 0; p.y = 0; p.z = 0; p.w = 0; }
      *(ushort4*)&As[m * 40 + kq] = p;
    }
#pragma unroll
    for (int i = 0; i < 2; i++) {
      int u = tid + i * 256;
      int k2 = u & 15, nq = (u >> 4) << 2;
      size_t o0 = (size_t)(k0 + 2 * k2) * N + bn + nq;
      const float4 g0 = *(const float4*)&gP[o0];
      const float4 g1 = *(const float4*)&gP[o0 + N];
      const float4 u0 = *(const float4*)&uP[o0];
      const float4 u1 = *(const float4*)&uP[o0 + N];
      *(unsigned*)&Gs[(nq + 0) * 40 + 2 * k2] = (unsigned)f2bf(g0.x) | ((unsigned)f2bf(g1.x) << 16);
      *(unsigned*)&Gs[(nq + 1) * 40 + 2 * k2] = (unsigned)f2bf(g0.y) | ((unsigned)f2bf(g1.y) << 16);
      *(unsigned*)&Gs[(nq + 2) * 40 + 2 * k2] = (unsigned)f2bf(g0.z) | ((unsigned)f2bf(g1.z) << 16);
      *(unsigned*)&Gs[(nq + 3) * 40 + 2 * k2] = (unsigned)f2bf(g0.w) | ((unsigned)f2bf(g1.w) << 16);
      *(unsigned*)&Us[(nq + 0) * 40 + 2 * k2] = (unsigned)f2bf(u0.x) | ((unsigned)f2bf(u1.x) << 16);
      *(unsigned*)&Us[(nq + 1) * 40 + 2 * k2] = (unsigned)f2bf(u0.y) | ((unsigned)f2bf(u1.y) << 16);
      *(unsigned*)&Us[(nq + 2) * 40 + 2 * k2] = (unsigned)f2bf(u0.z) | ((unsigned)f2bf(u1.z) << 16);
      *(unsigned*)&Us[(nq + 3) * 40 + 2 * k2] = (unsigned)f2bf(u0.w) | ((unsigned)f2bf(u1.w) << 16);
    }
    __syncthreads();
    short8 af[4], gf[4], uf[4];
#pragma unroll
    for (int mt = 0; mt < 4; mt++) af[mt] = *(short8*)&As[(wy + mt * 16 + lm) * 40 + lk * 8];
#pragma unroll
    for (int nt = 0; nt < 4; nt++) { gf[nt] = *(short8*)&Gs[(wx + nt * 16 + lm) * 40 + lk * 8];
                                     uf[nt] = *(short8*)&Us[(wx + nt * 16 + lm) * 40 + lk * 8]; }
#pragma unroll
    for (int mt = 0; mt < 4; mt++)
#pragma unroll
      for (int nt = 0; nt < 4; nt++) {
        ag[mt][nt] = __builtin_amdgcn_mfma_f32_16x16x32_bf16(af[mt], gf[nt], ag[mt][nt], 0, 0, 0);
        au[mt][nt] = __builtin_amdgcn_mfma_f32_16x16x32_bf16(af[mt], uf[nt], au[mt][nt], 0, 0, 0);
      }
    __syncthreads();
  }
#pragma unroll
  for (int mt = 0; mt < 4; mt++) {
#pragma unroll
    for (int nt = 0; nt < 4; nt++) {
#pragma unroll
      for (int r = 0; r < 4; r++) {
        int gm = bm + wy + mt * 16 + lk * 4 + r;
        if (gm >= n_rows) continue;
        int n = bn + wx + nt * 16 + lm;
        float gv = ag[mt][nt][r], uv = au[mt][nt][r];
        oP[(size_t)gm * N + n] = gv * (1.0f / (1.0f + expf(-gv))) * uv;
      }
    }
  }
}

// down: C_scatter[tok] += w * (hmid[e] @ wd[e]) ; A compact per expert.
__global__ __launch_bounds__(256) void k_down_bf16(const float* __restrict__ hmid, const float* __restrict__ wd,
                                                   const int* __restrict__ toki, const float* __restrict__ tokw,
                                                   const int* __restrict__ cnt, float* __restrict__ out) {
  int e = blockIdx.z;
  int n_rows = cnt[e];
  int bm = blockIdx.y * 128;
  if (bm >= n_rows) return;
  int bn = blockIdx.x * 128;
  const float* A = hmid + (size_t)e * kT * kF;
  const float* B = wd + (size_t)e * kF * kD;
  __shared__ __align__(16) unsigned short As[128 * 40];
  __shared__ __align__(16) unsigned short Bs[128 * 40];
  int tid = threadIdx.x;
  int wave = tid >> 6, lane = tid & 63;
  int wy = (wave >> 1) * 64, wx = (wave & 1) * 64;
  int lm = lane & 15, lk = lane >> 4;
  floatx4 acc[4][4] = {};
  for (int k0 = 0; k0 < kF; k0 += 32) {
#pragma unroll
    for (int i = 0; i < 4; i++) {
      int lin = tid + i * 256;
      int m = lin >> 3, kq = (lin & 7) << 2;
      ushort4 p;
      if (bm + m < n_rows) {
        const float4 a4 = *(const float4*)&A[(size_t)(bm + m) * kF + k0 + kq];
        p.x = f2bf(a4.x); p.y = f2bf(a4.y); p.z = f2bf(a4.z); p.w = f2bf(a4.w);
      } else { p.x = 0; p.y = 0; p.z = 0; p.w = 0; }
      *(ushort4*)&As[m * 40 + kq] = p;
    }
#pragma unroll
    for (int i = 0; i < 2; i++) {
      int u = tid + i * 256;
      int k2 = u & 15, nq = (u >> 4) << 2;
      size_t o0 = (size_t)(k0 + 2 * k2) * kD + bn + nq;
      const float4 b0 = *(const float4*)&B[o0];
      const float4 b1 = *(const float4*)&B[o0 + kD];
      *(unsigned*)&Bs[(nq + 0) * 40 + 2 * k2] = (unsigned)f2bf(b0.x) | ((unsigned)f2bf(b1.x) << 16);
      *(unsigned*)&Bs[(nq + 1) * 40 + 2 * k2] = (unsigned)f2bf(b0.y) | ((unsigned)f2bf(b1.y) << 16);
      *(unsigned*)&Bs[(nq + 2) * 40 + 2 * k2] = (unsigned)f2bf(b0.z) | ((unsigned)f2bf(b1.z) << 16);
      *(unsigned*)&Bs[(nq + 3) * 40 + 2 * k2] = (unsigned)f2bf(b0.w) | ((unsigned)f2bf(b1.w) << 16);
    }
    __syncthreads();
    short8 af[4], bfr[4];
#pragma unroll
    for (int mt = 0; mt < 4; mt++) af[mt] = *(short8*)&As[(wy + mt * 16 + lm) * 40 + lk * 8];
#pragma unroll
    for (int nt = 0; nt < 4; nt++) bfr[nt] = *(short8*)&Bs[(wx + nt * 16 + lm) * 40 + lk * 8];
#pragma unroll
    for (int mt = 0; mt < 4; mt++)
#pragma unroll
      for (int nt = 0; nt < 4; nt++)
        acc[mt][nt] = __builtin_amdgcn_mfma_f32_16x16x32_bf16(af[mt], bfr[nt], acc[mt][nt], 0, 0, 0);
    __syncthreads();
  }
#pragma unroll
  for (int mt = 0; mt < 4; mt++) {
#pragma unroll
    for (int r = 0; r < 4; r++) {
      int gm = bm + wy + mt * 16 + lk * 4 + r;
      if (gm >= n_rows) continue;
      int tt = toki[e * kT + gm];
      float w = tokw[e * kT + gm];
#pragma unroll
      for (int nt = 0; nt < 4; nt++) {
        int n = bn + wx + nt * 16 + lm;
        atomicAdd(&out[(size_t)tt * kD + n], w * acc[mt][nt][r]);
      }
    }
  }
}

// ---------------- f32 kernels (unchanged paths) ----------------

__global__ __launch_bounds__(256) void k_add_rms(const float* __restrict__ h, const float* __restrict__ r,
                                                 const float* __restrict__ w, float* __restrict__ resid,
                                                 float* __restrict__ out) {
  __shared__ float row[kD];
  __shared__ float red[4];
  int t = blockIdx.x;
  size_t base = (size_t)t * kD;
  float ss = 0.f;
  for (int c = threadIdx.x; c < kD; c += 256) {
    float v = h[base + c] + r[base + c];
    row[c] = v; resid[base + c] = v; ss += v * v;
  }
  float tot = bsum256(ss, red);
  float inv = 1.0f / sqrtf(tot * (1.0f / kD) + 1e-6f);
  for (int c = threadIdx.x; c < kD; c += 256) out[base + c] = row[c] * inv * w[c];
}

__global__ __launch_bounds__(256) void k_rms_rows(const float* __restrict__ in, int stride, int off,
                                                  const float* __restrict__ w, float* __restrict__ out, int cols) {
  __shared__ float row[kD];
  __shared__ float red[4];
  int t = blockIdx.x;
  const float* x = in + (size_t)t * stride + off;
  float ss = 0.f;
  for (int c = threadIdx.x; c < cols; c += 256) { float v = x[c]; row[c] = v; ss += v * v; }
  float tot = bsum256(ss, red);
  float inv = 1.0f / sqrtf(tot / (float)cols + 1e-6f);
  for (int c = threadIdx.x; c < cols; c += 256) out[(size_t)t * cols + c] = row[c] * inv * w[c];
}

__global__ __launch_bounds__(256) void k_gemm(const float* __restrict__ A, const float* __restrict__ B,
                                              float* __restrict__ C, int M, int N, int K,
                                              const float* __restrict__ addend) {
  __shared__ float As[16][68];
  __shared__ float Bs[16][68];
  int bm = blockIdx.y * 64, bn = blockIdx.x * 64;
  int tid = threadIdx.x, tx = tid & 15, ty = tid >> 4;
  int tx4 = tx * 4, ty4 = ty * 4;
  int ar = tid >> 2, ak = (tid & 3) << 2;
  int brk = tid >> 4, bn0 = (tid & 15) << 2;
  float acc[4][4] = {};
  for (int k0 = 0; k0 < K; k0 += 16) {
    {
      int gm = bm + ar;
      if (gm < M) {
        const float4 a4 = *(const float4*)&A[(size_t)gm * K + k0 + ak];
        As[ak][ar] = a4.x; As[ak + 1][ar] = a4.y; As[ak + 2][ar] = a4.z; As[ak + 3][ar] = a4.w;
      } else {
        As[ak][ar] = 0.f; As[ak + 1][ar] = 0.f; As[ak + 2][ar] = 0.f; As[ak + 3][ar] = 0.f;
      }
    }
    {
      int gk = k0 + brk;
      int gn = bn + bn0;
      if (gn + 3 < N) {
        const float4 b4 = *(const float4*)&B[(size_t)gk * N + gn];
        Bs[brk][bn0] = b4.x; Bs[brk][bn0 + 1] = b4.y; Bs[brk][bn0 + 2] = b4.z; Bs[brk][bn0 + 3] = b4.w;
      } else {
#pragma unroll
        for (int i = 0; i < 4; i++) Bs[brk][bn0 + i] = (gn + i < N) ? B[(size_t)gk * N + gn + i] : 0.f;
      }
    }
    __syncthreads();
#pragma unroll
    for (int kk = 0; kk < 16; kk++) {
      float a0 = As[kk][ty4], a1 = As[kk][ty4 + 1], a2 = As[kk][ty4 + 2], a3 = As[kk][ty4 + 3];
      float b0 = Bs[kk][tx4], b1 = Bs[kk][tx4 + 1], b2 = Bs[kk][tx4 + 2], b3 = Bs[kk][tx4 + 3];
      acc[0][0] += a0 * b0; acc[0][1] += a0 * b1; acc[0][2] += a0 * b2; acc[0][3] += a0 * b3;
      acc[1][0] += a1 * b0; acc[1][1] += a1 * b1; acc[1][2] += a1 * b2; acc[1][3] += a1 * b3;
      acc[2][0] += a2 * b0; acc[2][1] += a2 * b1; acc[2][2] += a2 * b2; acc[2][3] += a2 * b3;
      acc[3][0] += a3 * b0; acc[3][1] += a3 * b1; acc[3][2] += a3 * b2; acc[3][3] += a3 * b3;
    }
    __syncthreads();
  }
#pragma unroll
  for (int i = 0; i < 4; i++) {
    int gm = bm + ty4 + i;
    if (gm >= M) continue;
#pragma unroll
    for (int j = 0; j < 4; j++) {
      int gn = bn + tx4 + j;
      if (gn >= N) continue;
      float v = acc[i][j];
      if (addend) v += addend[(size_t)gm * N + gn];
      C[(size_t)gm * N + gn] = v;
    }
  }
}

__global__ __launch_bounds__(256) void k_rope_q(float* __restrict__ q, const int* __restrict__ pos) {
  int t = blockIdx.x;
  float p = (float)pos[t];
  for (int idx = threadIdx.x; idx < kH * 32; idx += 256) {
    int h = idx >> 5, j = idx & 31;
    float invf = 1.0f / powf(10000.0f, (float)j * 0.03125f);
    float ang = p * invf; float s, c; sincosf(ang, &s, &c);
    size_t base = ((size_t)t * kH + h) * kQKD + kNOPE + 2 * j;
    float x1 = q[base], x2 = q[base + 1];
    q[base] = x1 * c - x2 * s;
    q[base + 1] = x2 * c + x1 * s;
  }
}

__global__ __launch_bounds__(256) void k_rope_iq(float* __restrict__ iq, const int* __restrict__ pos) {
  int t = blockIdx.x;
  float p = (float)pos[t];
  for (int idx = threadIdx.x; idx < kIH * 32; idx += 256) {
    int h = idx >> 5, j = idx & 31;
    float invf = 1.0f / powf(10000.0f, (float)j * 0.03125f);
    float ang = p * invf; float s, c; sincosf(ang, &s, &c);
    size_t base = ((size_t)t * kIH + h) * kID + 2 * j;
    float x1 = iq[base], x2 = iq[base + 1];
    iq[base] = x1 * c - x2 * s;
    iq[base + 1] = x2 * c + x1 * s;
  }
}

__global__ __launch_bounds__(64) void k_rope_kpe(const float* __restrict__ qkv, const int* __restrict__ pos,
                                                 float* __restrict__ kpe) {
  int t = blockIdx.x; int j = threadIdx.x;
  if (j >= 32) return;
  float p = (float)pos[t];
  float invf = 1.0f / powf(10000.0f, (float)j * 0.03125f);
  float ang = p * invf; float s, c; sincosf(ang, &s, &c);
  const float* src = qkv + (size_t)t * kQKV_N + kQL + kKVL;
  float x1 = src[2 * j], x2 = src[2 * j + 1];
  kpe[(size_t)t * 64 + 2 * j] = x1 * c - x2 * s;
  kpe[(size_t)t * 64 + 2 * j + 1] = x2 * c + x1 * s;
}

__global__ __launch_bounds__(64) void k_quant_rows(float* __restrict__ x, float* __restrict__ scales) {
  int row = blockIdx.x;
  float* p = x + (size_t)row * kID;
  int l = threadIdx.x;
  float v0 = p[2 * l], v1 = p[2 * l + 1];
  float am = wmax64(fmaxf(fabsf(v0), fabsf(v1)));
  float scale = pow2ceil(fmaxf(am / 448.0f, 1e-10f));
  float inv = 1.0f / scale;
  p[2 * l]     = fp8q(fminf(fmaxf(v0 * inv, -448.f), 448.f));
  p[2 * l + 1] = fp8q(fminf(fmaxf(v1 * inv, -448.f), 448.f));
  if (l == 0) scales[row] = scale;
}

__global__ __launch_bounds__(64) void k_ik_process(const float* __restrict__ raw, const float* __restrict__ w,
                                                   const float* __restrict__ b, const int* __restrict__ pos,
                                                   float* __restrict__ outq, float* __restrict__ scales) {
  int t = blockIdx.x; int l = threadIdx.x;
  const float* x = raw + (size_t)t * kID;
  float x0 = x[2 * l], x1 = x[2 * l + 1];
  float mean = wsum(x0 + x1) * (1.0f / 128.0f);
  float d0 = x0 - mean, d1 = x1 - mean;
  float var = wsum(d0 * d0 + d1 * d1) * (1.0f / 128.0f);
  float inv = 1.0f / sqrtf(var + 1e-6f);
  float y0 = d0 * inv * w[2 * l] + b[2 * l];
  float y1 = d1 * inv * w[2 * l + 1] + b[2 * l + 1];
  if (l < 32) {
    float p = (float)pos[t];
    float invf = 1.0f / powf(10000.0f, (float)l * 0.03125f);
    float ang = p * invf; float sn, cs; sincosf(ang, &sn, &cs);
    float r0 = y0 * cs - y1 * sn, r1 = y1 * cs + y0 * sn;
    y0 = r0; y1 = r1;
  }
  float am = wmax64(fmaxf(fabsf(y0), fabsf(y1)));
  float scale = pow2ceil(fmaxf(am / 448.0f, 1e-10f));
  float is = 1.0f / scale;
  outq[(size_t)t * kID + 2 * l]     = fp8q(fminf(fmaxf(y0 * is, -448.f), 448.f));
  outq[(size_t)t * kID + 2 * l + 1] = fp8q(fminf(fmaxf(y1 * is, -448.f), 448.f));
  if (l == 0) scales[t] = scale;
}

__global__ __launch_bounds__(256) void k_iw(const float* __restrict__ raw, const float* __restrict__ sc,
                                            float* __restrict__ out) {
  int i = blockIdx.x * 256 + threadIdx.x;
  if (i < kT * kIH) out[i] = raw[i] * sc[i] * 0.08838834764831845f * 0.17677669529663687f;
}

__global__ __launch_bounds__(256) void k_scores(const float* __restrict__ iq, const float* __restrict__ ik,
                                                const float* __restrict__ iksc, const float* __restrict__ iw,
                                                float* __restrict__ scores) {
  __shared__ __align__(16) float iqs[kIH * kID];
  __shared__ float iws[kIH];
  int t = blockIdx.x;
  for (int i = threadIdx.x; i < kIH * kID; i += 256) iqs[i] = iq[(size_t)t * kIH * kID + i];
  if (threadIdx.x < kIH) iws[threadIdx.x] = iw[t * kIH + threadIdx.x];
  __syncthreads();
  for (int s = threadIdx.x; s <= t; s += 256) {
    float acc[kIH];
#pragma unroll
    for (int h = 0; h < kIH; h++) acc[h] = 0.f;
    const float4* kr = (const float4*)(ik + (size_t)s * kID);
    for (int d4 = 0; d4 < kID / 4; d4++) {
      float4 kv4 = kr[d4];
#pragma unroll
      for (int h = 0; h < kIH; h++) {
        const float4 q4 = *(const float4*)&iqs[h * kID + d4 * 4];
        acc[h] += q4.x * kv4.x + q4.y * kv4.y + q4.z * kv4.z + q4.w * kv4.w;
      }
    }
    float scv = iksc[s];
    float tot = 0.f;
#pragma unroll
    for (int h = 0; h < kIH; h++) tot += iws[h] * fmaxf(acc[h] * scv, 0.f);
    scores[(size_t)t * kT + s] = tot;
  }
}

__global__ __launch_bounds__(64) void k_topk(const float* __restrict__ scores, unsigned char* __restrict__ mask) {
  int t = blockIdx.x; int l = threadIdx.x;
  unsigned char* mrow = mask + (size_t)t * kT;
  if (t < kTOPK) {
    for (int s = l; s < kT; s += 64) mrow[s] = (s <= t) ? 1 : 0;
    return;
  }
  unsigned key[16];
  const float* srow = scores + (size_t)t * kT;
#pragma unroll
  for (int i = 0; i < 16; i++) {
    int s = l * 16 + i;
    key[i] = (s <= t) ? sortkey(srow[s]) : 0u;
  }
  unsigned prefix = 0; int remaining = kTOPK;
  for (int bit = 31; bit >= 0; bit--) {
    unsigned himask = 0xFFFFFFFFu << bit;
    unsigned cmp = prefix | (1u << bit);
    int c = 0;
#pragma unroll
    for (int i = 0; i < 16; i++) c += ((key[i] & himask) == cmp) ? 1 : 0;
    c = wsum_i(c);
    if (c >= remaining) prefix = cmp; else remaining -= c;
  }
  int ceq = 0, cgt = 0;
#pragma unroll
  for (int i = 0; i < 16; i++) { ceq += (key[i] == prefix) ? 1 : 0; cgt += (key[i] > prefix) ? 1 : 0; }
  int v = ceq;
#pragma unroll
  for (int o = 1; o < 64; o <<= 1) { int u = __shfl_up(v, o, 64); if (l >= o) v += u; }
  int rank = v - ceq;
  int need = kTOPK - wsum_i(cgt);
#pragma unroll
  for (int i = 0; i < 16; i++) {
    int s = l * 16 + i;
    unsigned char sel;
    if (key[i] > prefix) sel = 1;
    else if (key[i] == prefix) { sel = (rank < need) ? 1 : 0; rank++; }
    else sel = 0;
    mrow[s] = sel;
  }
}

__global__ __launch_bounds__(256) void k_attn(const float* __restrict__ q, const float* __restrict__ kv,
                                              const float* __restrict__ kpe, const unsigned char* __restrict__ mask,
                                              float* __restrict__ o) {
  __shared__ float att[8][kT];
  __shared__ __align__(16) float kq[32 * 196 + 8 * 196];
  float* qs = kq + 32 * 196;
  int h = blockIdx.y;
  int t0 = blockIdx.x * 8;
  int tid = threadIdx.x;
  int t_max = t0 + 7;
  for (int idx = tid; idx < 8 * 192; idx += 256) {
    int tq = idx / 192, d = idx - tq * 192;
    qs[tq * 196 + d] = q[((size_t)(t0 + tq) * kH + h) * kQKD + d];
  }
  __syncthreads();
  int tq = tid >> 5, sl = tid & 31;
  int t_row = t0 + tq;
  const unsigned char* mrow = mask + (size_t)t_row * kT;
  int nch = (t_max >> 5) + 1;
  for (int ch = 0; ch < nch; ch++) {
    int sc = ch << 5;
    for (int idx = tid; idx < 32 * 192; idx += 256) {
      int sr = idx / 192, d = idx - sr * 192;
      int s = sc + sr;
      float v = 0.f;
      if (s < kT) v = (d < 128) ? kv[((size_t)s * kH + h) * 256 + d] : kpe[(size_t)s * 64 + (d - 128)];
      kq[sr * 196 + d] = v;
    }
    __syncthreads();
    int s = sc + sl;
    if (s <= t_max) {
      float a = -1e30f;
      if (mrow[s]) {
        float accd = 0.f;
        const float4* qv = (const float4*)(qs + tq * 196);
        const float4* kr = (const float4*)(kq + sl * 196);
#pragma unroll
        for (int d4 = 0; d4 < 48; d4++) {
          float4 x = qv[d4], y = kr[d4];
          accd += x.x * y.x + x.y * y.y + x.z * y.z + x.w * y.w;
        }
        a = accd * 0.07216878364870323f;
      }
      att[tq][s] = a;
    }
    __syncthreads();
  }
  float m = -1e30f;
  for (int s = sl; s <= t_max; s += 32) m = fmaxf(m, att[tq][s]);
#pragma unroll
  for (int o2 = 16; o2; o2 >>= 1) m = fmaxf(m, __shfl_xor(m, o2, 32));
  float lsum = 0.f;
  for (int s = sl; s <= t_max; s += 32) { float p = expf(att[tq][s] - m); att[tq][s] = p; lsum += p; }
#pragma unroll
  for (int o2 = 16; o2; o2 >>= 1) lsum += __shfl_xor(lsum, o2, 32);
  float inv = 1.0f / lsum;
  __syncthreads();
  float oa0 = 0, oa1 = 0, oa2 = 0, oa3 = 0;
  float* vb = kq;
  for (int ch = 0; ch < nch; ch++) {
    int sc = ch << 5;
    for (int idx = tid; idx < 32 * 128; idx += 256) {
      int sr = idx >> 7, d = idx & 127;
      int s = sc + sr;
      vb[sr * 128 + d] = (s < kT) ? kv[((size_t)s * kH + h) * 256 + 128 + d] : 0.f;
    }
    __syncthreads();
    int smax = t_max - sc; if (smax > 31) smax = 31;
    for (int j = 0; j <= smax; j++) {
      float p = att[tq][sc + j];
      const float4 v4 = *(const float4*)&vb[j * 128 + sl * 4];
      oa0 += p * v4.x; oa1 += p * v4.y; oa2 += p * v4.z; oa3 += p * v4.w;
    }
    __syncthreads();
  }
  float4 res; res.x = oa0 * inv; res.y = oa1 * inv; res.z = oa2 * inv; res.w = oa3 * inv;
  *(float4*)&o[((size_t)t_row * kH + h) * kVD + sl * 4] = res;
}

__global__ __launch_bounds__(64) void k_route(const float* __restrict__ hs2, const float* __restrict__ wg,
                                              int* __restrict__ cnt, int* __restrict__ toki,
                                              float* __restrict__ tokw) {
  int t = blockIdx.x; int l = threadIdx.x;
  float acc[8] = {};
  for (int d = l; d < kD; d += 64) {
    float hv = hs2[(size_t)t * kD + d];
    const float* wr = wg + (size_t)d * 8;
#pragma unroll
    for (int e = 0; e < 8; e++) acc[e] += hv * wr[e];
  }
#pragma unroll
  for (int e = 0; e < 8; e++) acc[e] = wsum(acc[e]);
  if (l == 0) {
    float g[8];
#pragma unroll
    for (int e = 0; e < 8; e++) g[e] = 1.0f / (1.0f + expf(-acc[e]));
    int i0 = 0;
    for (int e = 1; e < 8; e++) if (g[e] > g[i0]) i0 = e;
    int i1 = (i0 == 0) ? 1 : 0;
    for (int e = 0; e < 8; e++) if (e != i0 && g[e] > g[i1]) i1 = e;
    float ssum = g[i0] + g[i1];
    float w0 = g[i0] / ssum * 2.5f, w1 = g[i1] / ssum * 2.5f;
    int s0 = atomicAdd(&cnt[i0], 1); toki[i0 * kT + s0] = t; tokw[i0 * kT + s0] = w0;
    int s1 = atomicAdd(&cnt[i1], 1); toki[i1 * kT + s1] = t; tokw[i1 * kT + s1] = w1;
  }
}

// ---------------- launch ----------------
extern "C" void kernel_launch(void* const* d_in, const int* in_sizes, int n_in,
                              void* d_out, int out_size, void* d_ws, size_t ws_size,
                              hipStream_t stream) {
  (void)in_sizes; (void)n_in; (void)out_size; (void)ws_size;
  const int*   positions  = (const int*)d_in[0];
  const float* hidden     = (const float*)d_in[1];
  const float* residual   = (const float*)d_in[2];
  const float* input_ln_w = (const float*)d_in[3];
  const float* post_ln_w  = (const float*)d_in[4];
  const float* w_qkv_a    = (const float*)d_in[5];
  const float* q_a_ln_w   = (const float*)d_in[6];
  const float* w_q_b      = (const float*)d_in[7];
  const float* kv_a_ln_w  = (const float*)d_in[8];
  const float* w_kv_b     = (const float*)d_in[9];
  const float* w_o        = (const float*)d_in[10];
  const float* w_idx_q_b  = (const float*)d_in[11];
  const float* w_idx_k    = (const float*)d_in[12];
  const float* idx_k_ln_w = (const float*)d_in[13];
  const float* idx_k_ln_b = (const float*)d_in[14];
  const float* w_idx_w    = (const float*)d_in[15];
  const float* w_gate     = (const float*)d_in[16];
  const float* w_moe_gate = (const float*)d_in[17];
  const float* w_moe_up   = (const float*)d_in[18];
  const float* w_moe_down = (const float*)d_in[19];
  const float* w_sh_gate  = (const float*)d_in[20];
  const float* w_sh_up    = (const float*)d_in[21];
  const float* w_sh_down  = (const float*)d_in[22];

  float* out0 = (float*)d_out;
  float* out1 = out0 + (size_t)kT * kD;

  float* W = (float*)d_ws;
  size_t off = 0;
  auto alloc = [&](size_t nfl) { float* p = W + off; off += nfl; return p; };
  float* resid   = alloc((size_t)kT * kD);
  float* hs      = alloc((size_t)kT * kD);
  float* qkv     = alloc((size_t)kT * kQKV_N);
  float* q_c     = alloc((size_t)kT * kQL);
  float* kv_cn   = alloc((size_t)kT * kKVL);
  float* qb      = alloc((size_t)kT * kH * kQKD);
  float* kvb     = alloc((size_t)kT * kH * 256);
  float* iqb     = alloc((size_t)kT * kIH * kID);
  float* ikraw   = alloc((size_t)kT * kID);
  float* ikb     = alloc((size_t)kT * kID);
  float* iksc    = alloc(kT);
  float* iqsc    = alloc((size_t)kT * kIH);
  float* iwraw   = alloc((size_t)kT * kIH);
  float* iwb     = alloc((size_t)kT * kIH);
  float* kpe     = alloc((size_t)kT * kROPE);
  float* scoresb = alloc((size_t)kT * kT);
  unsigned char* maskb = (unsigned char*)alloc((size_t)kT * kT / 4);
  float* o_attn  = alloc((size_t)kT * kH * kVD);
  float* hs2     = alloc((size_t)kT * kD);
  float* sg      = alloc((size_t)kT * kF);
  float* hmid    = alloc((size_t)kE * kT * kF);
  float* tokw    = alloc((size_t)kE * kT);
  int*   toki    = (int*)alloc((size_t)kE * kT);
  int*   cnt     = (int*)alloc(16);

  k_add_rms<<<kT, 256, 0, stream>>>(hidden, residual, input_ln_w, resid, hs);
  // qkv_a + index path stay f32 (protect fp8/topk selection from bf16 drift)
  { dim3 g((kQKV_N + 63) / 64, kT / 64); k_gemm<<<g, 256, 0, stream>>>(hs, w_qkv_a, qkv, kT, kQKV_N, kD, nullptr); }
  k_rms_rows<<<kT, 256, 0, stream>>>(qkv, kQKV_N, 0, q_a_ln_w, q_c, kQL);
  k_rms_rows<<<kT, 256, 0, stream>>>(qkv, kQKV_N, kQL, kv_a_ln_w, kv_cn, kKVL);
  { dim3 g(kH * kQKD / 128, kT / 128); k_gemm_bf16<<<g, 256, 0, stream>>>(q_c, w_q_b, qb, nullptr, kT, kH * kQKD, kQL); }
  { dim3 g((kIH * kID) / 64, kT / 64); k_gemm<<<g, 256, 0, stream>>>(q_c, w_idx_q_b, iqb, kT, kIH * kID, kQL, nullptr); }
  { dim3 g(kH * 256 / 128, kT / 128); k_gemm_bf16<<<g, 256, 0, stream>>>(kv_cn, w_kv_b, kvb, nullptr, kT, kH * 256, kKVL); }
  { dim3 g(2, kT / 64); k_gemm<<<g, 256, 0, stream>>>(hs, w_idx_k, ikraw, kT, kID, kD, nullptr); }
  { dim3 g(1, kT / 64); k_gemm<<<g, 256, 0, stream>>>(hs, w_idx_w, iwraw, kT, kIH, kD, nullptr); }
  k_rope_q<<<kT, 256, 0, stream>>>(qb, positions);
  k_rope_iq<<<kT, 256, 0, stream>>>(iqb, positions);
  k_rope_kpe<<<kT, 64, 0, stream>>>(qkv, positions, kpe);
  k_quant_rows<<<kT * kIH, 64, 0, stream>>>(iqb, iqsc);
  k_ik_process<<<kT, 64, 0, stream>>>(ikraw, idx_k_ln_w, idx_k_ln_b, positions, ikb, iksc);
  k_iw<<<(kT * kIH + 255) / 256, 256, 0, stream>>>(iwraw, iqsc, iwb);
  k_scores<<<kT, 256, 0, stream>>>(iqb, ikb, iksc, iwb, scoresb);
  k_topk<<<kT, 64, 0, stream>>>(scoresb, maskb);
  { dim3 g(kT / 8, kH); k_attn<<<g, 256, 0, stream>>>(qb, kvb, kpe, maskb, o_attn); }
  { dim3 g(kD / 128, kT / 128); k_gemm_bf16<<<g, 256, 0, stream>>>(o_attn, w_o, out1, resid, kT, kD, kH * kVD); }
  k_rms_rows<<<kT, 256, 0, stream>>>(out1, kD, 0, post_ln_w, hs2, kD);
  hipMemsetAsync(cnt, 0, 8 * sizeof(int), stream);
  k_route<<<kT, 64, 0, stream>>>(hs2, w_gate, cnt, toki, tokw);
  // shared FFN: fused dual gate/up + silu (no gather)
  { dim3 g(kF / 128, kT / 128, 1); k_dual_bf16<<<g, 256, 0, stream>>>(hs2, w_sh_gate, w_sh_up, sg, nullptr, nullptr, kT, kF, kD); }
  { dim3 g(kD / 128, kT / 128); k_gemm_bf16<<<g, 256, 0, stream>>>(sg, w_sh_down, out0, nullptr, kT, kD, kF); }
  // MoE: gathered dual gate/up + silu, then gathered down with atomic scatter
  { dim3 g(kF / 128, kT / 128, kE); k_dual_bf16<<<g, 256, 0, stream>>>(hs2, w_moe_gate, w_moe_up, hmid, toki, cnt, kT, kF, kD); }
  { dim3 g(kD / 128, kT / 128, kE); k_down_bf16<<<g, 256, 0, stream>>>(hmid, w_moe_down, toki, tokw, cnt, out0); }
}

// Round 3
// 1881.987 us; speedup vs baseline: 1.9426x; 1.5277x over previous
//
#include <hip/hip_runtime.h>

namespace {
constexpr int kT = 1024, kD = 2048, kH = 16, kNOPE = 128, kROPE = 64, kVD = 128, kQKD = 192;
constexpr int kQL = 768, kKVL = 512, kIH = 32, kID = 128, kTOPK = 256, kE = 8, kF = 1024;
constexpr int kQKV_N = kQL + kKVL + kROPE; // 1344
}

typedef __attribute__((ext_vector_type(4))) float floatx4;
typedef __attribute__((ext_vector_type(8))) short short8;

// ---------------- device helpers ----------------
__device__ __forceinline__ float wsum(float v) {
#pragma unroll
  for (int o = 32; o; o >>= 1) v += __shfl_xor(v, o, 64);
  return v;
}
__device__ __forceinline__ float wmax64(float v) {
#pragma unroll
  for (int o = 32; o; o >>= 1) v = fmaxf(v, __shfl_xor(v, o, 64));
  return v;
}
__device__ __forceinline__ int wsum_i(int v) {
#pragma unroll
  for (int o = 32; o; o >>= 1) v += __shfl_xor(v, o, 64);
  return v;
}
__device__ __forceinline__ float bsum256(float v, float* red) {
  v = wsum(v);
  if ((threadIdx.x & 63) == 0) red[threadIdx.x >> 6] = v;
  __syncthreads();
  float t = red[0] + red[1] + red[2] + red[3];
  __syncthreads();
  return t;
}
__device__ __forceinline__ unsigned sortkey(float f) {
  unsigned b = __float_as_uint(f);
  return (b & 0x80000000u) ? ~b : (b | 0x80000000u);
}
__device__ __forceinline__ float pow2ceil(float z) {
  unsigned b = __float_as_uint(z);
  if ((b & 0x7FFFFFu) == 0) return z;
  return __uint_as_float((((b >> 23) & 0xFFu) + 1u) << 23);
}
__device__ __forceinline__ float fp8q(float x) {
  float ax = fabsf(x);
  float q;
  if (ax < 0.015625f) {
    q = rintf(ax * 512.0f) * 0.001953125f;
  } else {
    unsigned b = __float_as_uint(ax);
    int e = (int)((b >> 23) & 0xFF) - 127;
    float quant = __uint_as_float((unsigned)(e - 3 + 127) << 23);
    float rq    = __uint_as_float((unsigned)(127 - (e - 3)) << 23);
    q = rintf(ax * rq) * quant;
  }
  return copysignf(q, x);
}
// f32 -> bf16 RNE
__device__ __forceinline__ unsigned short f2bf(float x) {
  unsigned u = __float_as_uint(x);
  u += 0x7FFFu + ((u >> 16) & 1u);
  return (unsigned short)(u >> 16);
}

// ---------------- MFMA bf16 GEMM family ----------------

__global__ __launch_bounds__(256) void k_gemm_bf16(const float* __restrict__ A, const float* __restrict__ B,
                                                   float* __restrict__ C, const float* __restrict__ addend,
                                                   int M, int N, int K) {
  __shared__ __align__(16) unsigned short As[128 * 40];
  __shared__ __align__(16) unsigned short Bs[128 * 40];
  int tid = threadIdx.x;
  int bm = blockIdx.y * 128, bn = blockIdx.x * 128;
  int wave = tid >> 6, lane = tid & 63;
  int wy = (wave >> 1) * 64, wx = (wave & 1) * 64;
  int lm = lane & 15, lk = lane >> 4;
  floatx4 acc[4][4] = {};
  for (int k0 = 0; k0 < K; k0 += 32) {
#pragma unroll
    for (int i = 0; i < 4; i++) {
      int lin = tid + i * 256;
      int m = lin >> 3, kq = (lin & 7) << 2;
      const float4 a4 = *(const float4*)&A[(size_t)(bm + m) * K + k0 + kq];
      ushort4 p; p.x = f2bf(a4.x); p.y = f2bf(a4.y); p.z = f2bf(a4.z); p.w = f2bf(a4.w);
      *(ushort4*)&As[m * 40 + kq] = p;
    }
#pragma unroll
    for (int i = 0; i < 2; i++) {
      int u = tid + i * 256;
      int k2 = u & 15, nq = (u >> 4) << 2;
      const float4 b0 = *(const float4*)&B[(size_t)(k0 + 2 * k2) * N + bn + nq];
      const float4 b1 = *(const float4*)&B[(size_t)(k0 + 2 * k2 + 1) * N + bn + nq];
      *(unsigned*)&Bs[(nq + 0) * 40 + 2 * k2] = (unsigned)f2bf(b0.x) | ((unsigned)f2bf(b1.x) << 16);
      *(unsigned*)&Bs[(nq + 1) * 40 + 2 * k2] = (unsigned)f2bf(b0.y) | ((unsigned)f2bf(b1.y) << 16);
      *(unsigned*)&Bs[(nq + 2) * 40 + 2 * k2] = (unsigned)f2bf(b0.z) | ((unsigned)f2bf(b1.z) << 16);
      *(unsigned*)&Bs[(nq + 3) * 40 + 2 * k2] = (unsigned)f2bf(b0.w) | ((unsigned)f2bf(b1.w) << 16);
    }
    __syncthreads();
    short8 af[4], bfr[4];
#pragma unroll
    for (int mt = 0; mt < 4; mt++) af[mt] = *(short8*)&As[(wy + mt * 16 + lm) * 40 + lk * 8];
#pragma unroll
    for (int nt = 0; nt < 4; nt++) bfr[nt] = *(short8*)&Bs[(wx + nt * 16 + lm) * 40 + lk * 8];
#pragma unroll
    for (int mt = 0; mt < 4; mt++)
#pragma unroll
      for (int nt = 0; nt < 4; nt++)
        acc[mt][nt] = __builtin_amdgcn_mfma_f32_16x16x32_bf16(af[mt], bfr[nt], acc[mt][nt], 0, 0, 0);
    __syncthreads();
  }
#pragma unroll
  for (int mt = 0; mt < 4; mt++) {
#pragma unroll
    for (int nt = 0; nt < 4; nt++) {
#pragma unroll
      for (int r = 0; r < 4; r++) {
        int m = bm + wy + mt * 16 + lk * 4 + r;
        int n = bn + wx + nt * 16 + lm;
        float v = acc[mt][nt][r];
        if (addend) v += addend[(size_t)m * N + n];
        C[(size_t)m * N + n] = v;
      }
    }
  }
}

__global__ __launch_bounds__(256) void k_dual_bf16(const float* __restrict__ A, const float* __restrict__ Bg,
                                                   const float* __restrict__ Bu, float* __restrict__ out,
                                                   const int* __restrict__ toki, const int* __restrict__ cnt,
                                                   int M, int N, int K) {
  int e = blockIdx.z;
  int n_rows = toki ? cnt[e] : M;
  int bm = blockIdx.y * 128;
  if (bm >= n_rows) return;
  int bn = blockIdx.x * 128;
  const int* tk = toki ? (toki + e * kT) : nullptr;
  const float* gP = Bg + (size_t)e * K * N;
  const float* uP = Bu + (size_t)e * K * N;
  float* oP = out + (size_t)e * kT * N;
  __shared__ __align__(16) unsigned short As[128 * 40];
  __shared__ __align__(16) unsigned short Gs[128 * 40];
  __shared__ __align__(16) unsigned short Us[128 * 40];
  int tid = threadIdx.x;
  int wave = tid >> 6, lane = tid & 63;
  int wy = (wave >> 1) * 64, wx = (wave & 1) * 64;
  int lm = lane & 15, lk = lane >> 4;
  int arow[4];
#pragma unroll
  for (int i = 0; i < 4; i++) {
    int lin = tid + i * 256;
    int m = lin >> 3;
    int gm = bm + m;
    arow[i] = (gm < n_rows) ? (tk ? tk[gm] : gm) : -1;
  }
  floatx4 ag[4][4] = {}, au[4][4] = {};
  for (int k0 = 0; k0 < K; k0 += 32) {
#pragma unroll
    for (int i = 0; i < 4; i++) {
      int lin = tid + i * 256;
      int m = lin >> 3, kq = (lin & 7) << 2;
      ushort4 p;
      if (arow[i] >= 0) {
        const float4 a4 = *(const float4*)&A[(size_t)arow[i] * K + k0 + kq];
        p.x = f2bf(a4.x); p.y = f2bf(a4.y); p.z = f2bf(a4.z); p.w = f2bf(a4.w);
      } else { p.x = 0; p.y = 0; p.z = 0; p.w = 0; }
      *(ushort4*)&As[m * 40 + kq] = p;
    }
#pragma unroll
    for (int i = 0; i < 2; i++) {
      int u = tid + i * 256;
      int k2 = u & 15, nq = (u >> 4) << 2;
      size_t o0 = (size_t)(k0 + 2 * k2) * N + bn + nq;
      const float4 g0 = *(const float4*)&gP[o0];
      const float4 g1 = *(const float4*)&gP[o0 + N];
      const float4 u0 = *(const float4*)&uP[o0];
      const float4 u1 = *(const float4*)&uP[o0 + N];
      *(unsigned*)&Gs[(nq + 0) * 40 + 2 * k2] = (unsigned)f2bf(g0.x) | ((unsigned)f2bf(g1.x) << 16);
      *(unsigned*)&Gs[(nq + 1) * 40 + 2 * k2] = (unsigned)f2bf(g0.y) | ((unsigned)f2bf(g1.y) << 16);
      *(unsigned*)&Gs[(nq + 2) * 40 + 2 * k2] = (unsigned)f2bf(g0.z) | ((unsigned)f2bf(g1.z) << 16);
      *(unsigned*)&Gs[(nq + 3) * 40 + 2 * k2] = (unsigned)f2bf(g0.w) | ((unsigned)f2bf(g1.w) << 16);
      *(unsigned*)&Us[(nq + 0) * 40 + 2 * k2] = (unsigned)f2bf(u0.x) | ((unsigned)f2bf(u1.x) << 16);
      *(unsigned*)&Us[(nq + 1) * 40 + 2 * k2] = (unsigned)f2bf(u0.y) | ((unsigned)f2bf(u1.y) << 16);
      *(unsigned*)&Us[(nq + 2) * 40 + 2 * k2] = (unsigned)f2bf(u0.z) | ((unsigned)f2bf(u1.z) << 16);
      *(unsigned*)&Us[(nq + 3) * 40 + 2 * k2] = (unsigned)f2bf(u0.w) | ((unsigned)f2bf(u1.w) << 16);
    }
    __syncthreads();
    short8 af[4], gf[4], uf[4];
#pragma unroll
    for (int mt = 0; mt < 4; mt++) af[mt] = *(short8*)&As[(wy + mt * 16 + lm) * 40 + lk * 8];
#pragma unroll
    for (int nt = 0; nt < 4; nt++) { gf[nt] = *(short8*)&Gs[(wx + nt * 16 + lm) * 40 + lk * 8];
                                     uf[nt] = *(short8*)&Us[(wx + nt * 16 + lm) * 40 + lk * 8]; }
#pragma unroll
    for (int mt = 0; mt < 4; mt++)
#pragma unroll
      for (int nt = 0; nt < 4; nt++) {
        ag[mt][nt] = __builtin_amdgcn_mfma_f32_16x16x32_bf16(af[mt], gf[nt], ag[mt][nt], 0, 0, 0);
        au[mt][nt] = __builtin_amdgcn_mfma_f32_16x16x32_bf16(af[mt], uf[nt], au[mt][nt], 0, 0, 0);
      }
    __syncthreads();
  }
#pragma unroll
  for (int mt = 0; mt < 4; mt++) {
#pragma unroll
    for (int nt = 0; nt < 4; nt++) {
#pragma unroll
      for (int r = 0; r < 4; r++) {
        int gm = bm + wy + mt * 16 + lk * 4 + r;
        if (gm >= n_rows) continue;
        int n = bn + wx + nt * 16 + lm;
        float gv = ag[mt][nt][r], uv = au[mt][nt][r];
        oP[(size_t)gm * N + n] = gv * (1.0f / (1.0f + expf(-gv))) * uv;
      }
    }
  }
}

__global__ __launch_bounds__(256) void k_down_bf16(const float* __restrict__ hmid, const float* __restrict__ wd,
                                                   const int* __restrict__ toki, const float* __restrict__ tokw,
                                                   const int* __restrict__ cnt, float* __restrict__ out) {
  int e = blockIdx.z;
  int n_rows = cnt[e];
  int bm = blockIdx.y * 128;
  if (bm >= n_rows) return;
  int bn = blockIdx.x * 128;
  const float* A = hmid + (size_t)e * kT * kF;
  const float* B = wd + (size_t)e * kF * kD;
  __shared__ __align__(16) unsigned short As[128 * 40];
  __shared__ __align__(16) unsigned short Bs[128 * 40];
  int tid = threadIdx.x;
  int wave = tid >> 6, lane = tid & 63;
  int wy = (wave >> 1) * 64, wx = (wave & 1) * 64;
  int lm = lane & 15, lk = lane >> 4;
  floatx4 acc[4][4] = {};
  for (int k0 = 0; k0 < kF; k0 += 32) {
#pragma unroll
    for (int i = 0; i < 4; i++) {
      int lin = tid + i * 256;
      int m = lin >> 3, kq = (lin & 7) << 2;
      ushort4 p;
      if (bm + m < n_rows) {
        const float4 a4 = *(const float4*)&A[(size_t)(bm + m) * kF + k0 + kq];
        p.x = f2bf(a4.x); p.y = f2bf(a4.y); p.z = f2bf(a4.z); p.w = f2bf(a4.w);
      } else { p.x = 0; p.y = 0; p.z = 0; p.w = 0; }
      *(ushort4*)&As[m * 40 + kq] = p;
    }
#pragma unroll
    for (int i = 0; i < 2; i++) {
      int u = tid + i * 256;
      int k2 = u & 15, nq = (u >> 4) << 2;
      size_t o0 = (size_t)(k0 + 2 * k2) * kD + bn + nq;
      const float4 b0 = *(const float4*)&B[o0];
      const float4 b1 = *(const float4*)&B[o0 + kD];
      *(unsigned*)&Bs[(nq + 0) * 40 + 2 * k2] = (unsigned)f2bf(b0.x) | ((unsigned)f2bf(b1.x) << 16);
      *(unsigned*)&Bs[(nq + 1) * 40 + 2 * k2] = (unsigned)f2bf(b0.y) | ((unsigned)f2bf(b1.y) << 16);
      *(unsigned*)&Bs[(nq + 2) * 40 + 2 * k2] = (unsigned)f2bf(b0.z) | ((unsigned)f2bf(b1.z) << 16);
      *(unsigned*)&Bs[(nq + 3) * 40 + 2 * k2] = (unsigned)f2bf(b0.w) | ((unsigned)f2bf(b1.w) << 16);
    }
    __syncthreads();
    short8 af[4], bfr[4];
#pragma unroll
    for (int mt = 0; mt < 4; mt++) af[mt] = *(short8*)&As[(wy + mt * 16 + lm) * 40 + lk * 8];
#pragma unroll
    for (int nt = 0; nt < 4; nt++) bfr[nt] = *(short8*)&Bs[(wx + nt * 16 + lm) * 40 + lk * 8];
#pragma unroll
    for (int mt = 0; mt < 4; mt++)
#pragma unroll
      for (int nt = 0; nt < 4; nt++)
        acc[mt][nt] = __builtin_amdgcn_mfma_f32_16x16x32_bf16(af[mt], bfr[nt], acc[mt][nt], 0, 0, 0);
    __syncthreads();
  }
#pragma unroll
  for (int mt = 0; mt < 4; mt++) {
#pragma unroll
    for (int r = 0; r < 4; r++) {
      int gm = bm + wy + mt * 16 + lk * 4 + r;
      if (gm >= n_rows) continue;
      int tt = toki[e * kT + gm];
      float w = tokw[e * kT + gm];
#pragma unroll
      for (int nt = 0; nt < 4; nt++) {
        int n = bn + wx + nt * 16 + lm;
        atomicAdd(&out[(size_t)tt * kD + n], w * acc[mt][nt][r]);
      }
    }
  }
}

// ---------------- flash MFMA attention ----------------
// block = (head, 64 q-rows); 4 waves, each owns 16 rows.
// mask (causal & topk-sel) is bit-packed: mbits[t][16] u64, bit b of word w <-> key s = w*64+b.
__global__ __launch_bounds__(256) void k_attn_mfma(const float* __restrict__ q, const float* __restrict__ kv,
                                                   const float* __restrict__ kpe,
                                                   const unsigned long long* __restrict__ mbits,
                                                   float* __restrict__ o) {
  __shared__ __align__(16) unsigned short Ks[64 * 200];   // [key][qkd], stride 200
  __shared__ __align__(16) unsigned short Vs[128 * 72];   // [vd][key], stride 72 (transposed)
  __shared__ __align__(16) unsigned short Ps[4 * 16 * 72];// per-wave P round-trip, stride 72
  int h = blockIdx.y;
  int qb = gridDim.x - 1 - blockIdx.x;  // big blocks launch first
  int qbase = qb * 64;
  int tid = threadIdx.x;
  int wave = tid >> 6, lane = tid & 63;
  int lm = lane & 15, lk = lane >> 4;
  // Q fragments in registers: A-operand rows = qbase + wave*16 + lm
  short8 qf[6];
  {
    const float* qrow = q + ((size_t)(qbase + wave * 16 + lm) * kH + h) * kQKD;
#pragma unroll
    for (int ks = 0; ks < 6; ks++) {
      const float4 a0 = *(const float4*)&qrow[ks * 32 + lk * 8];
      const float4 a1 = *(const float4*)&qrow[ks * 32 + lk * 8 + 4];
      short8 f;
      f[0] = (short)f2bf(a0.x); f[1] = (short)f2bf(a0.y); f[2] = (short)f2bf(a0.z); f[3] = (short)f2bf(a0.w);
      f[4] = (short)f2bf(a1.x); f[5] = (short)f2bf(a1.y); f[6] = (short)f2bf(a1.z); f[7] = (short)f2bf(a1.w);
      qf[ks] = f;
    }
  }
  float m_r[4] = {-1e30f, -1e30f, -1e30f, -1e30f};
  float l_r[4] = {};
  floatx4 Oacc[8] = {};
  int sr = tid >> 2, sj = tid & 3;  // staging: 64 rows x 4 threads
  int nch = qb + 1;
  for (int ch = 0; ch < nch; ch++) {
    int s0 = ch << 6;
    __syncthreads();
    // stage K chunk: 64 keys x 192 (nope 128 from kv, rope 64 from kpe)
    {
      const float* kvrow = kv + ((size_t)(s0 + sr) * kH + h) * 256;
      const float* kprow = kpe + (size_t)(s0 + sr) * 64;
#pragma unroll
      for (int i = 0; i < 12; i++) {
        int c4 = (i << 2) + sj;
        float4 v4 = (c4 < 32) ? *(const float4*)&kvrow[c4 * 4] : *(const float4*)&kprow[(c4 - 32) * 4];
        ushort4 p; p.x = f2bf(v4.x); p.y = f2bf(v4.y); p.z = f2bf(v4.z); p.w = f2bf(v4.w);
        *(ushort4*)&Ks[sr * 200 + c4 * 4] = p;
      }
      // stage V chunk transposed: Vs[vd][key]
      const float* vrow = kvrow + 128;
#pragma unroll
      for (int i = 0; i < 8; i++) {
        int c4 = (i << 2) + sj;
        float4 v4 = *(const float4*)&vrow[c4 * 4];
        Vs[(c4 * 4 + 0) * 72 + sr] = f2bf(v4.x);
        Vs[(c4 * 4 + 1) * 72 + sr] = f2bf(v4.y);
        Vs[(c4 * 4 + 2) * 72 + sr] = f2bf(v4.z);
        Vs[(c4 * 4 + 3) * 72 + sr] = f2bf(v4.w);
      }
    }
    __syncthreads();
    // QK^T: 16 rows x 64 keys
    floatx4 sacc[4] = {};
#pragma unroll
    for (int ks = 0; ks < 6; ks++) {
      short8 kf[4];
#pragma unroll
      for (int nt = 0; nt < 4; nt++) kf[nt] = *(short8*)&Ks[(nt * 16 + lm) * 200 + ks * 32 + lk * 8];
#pragma unroll
      for (int nt = 0; nt < 4; nt++)
        sacc[nt] = __builtin_amdgcn_mfma_f32_16x16x32_bf16(qf[ks], kf[nt], sacc[nt], 0, 0, 0);
    }
    // mask + online softmax. C-layout: row = lk*4 + r, col = nt*16 + lm.
    unsigned long long mw[4];
#pragma unroll
    for (int r = 0; r < 4; r++) mw[r] = mbits[(size_t)(qbase + wave * 16 + lk * 4 + r) * 16 + ch];
    float mx[4] = {-1e30f, -1e30f, -1e30f, -1e30f};
#pragma unroll
    for (int nt = 0; nt < 4; nt++)
#pragma unroll
      for (int r = 0; r < 4; r++) {
        int sel = (int)((mw[r] >> (nt * 16 + lm)) & 1ull);
        float sv = sel ? sacc[nt][r] * 0.07216878364870323f : -1e30f;
        sacc[nt][r] = sv;
        mx[r] = fmaxf(mx[r], sv);
      }
#pragma unroll
    for (int off = 1; off < 16; off <<= 1)
#pragma unroll
      for (int r = 0; r < 4; r++) mx[r] = fmaxf(mx[r], __shfl_xor(mx[r], off, 64));
    float al[4], psum[4] = {};
#pragma unroll
    for (int r = 0; r < 4; r++) {
      float mnew = fmaxf(m_r[r], mx[r]);
      al[r] = __expf(m_r[r] - mnew);
      m_r[r] = mnew;
    }
#pragma unroll
    for (int nt = 0; nt < 4; nt++)
#pragma unroll
      for (int r = 0; r < 4; r++) {
        float p = (sacc[nt][r] > -0.9e30f) ? __expf(sacc[nt][r] - m_r[r]) : 0.0f;
        psum[r] += p;
        Ps[wave * 1152 + (lk * 4 + r) * 72 + nt * 16 + lm] = f2bf(p);
      }
#pragma unroll
    for (int off = 1; off < 16; off <<= 1)
#pragma unroll
      for (int r = 0; r < 4; r++) psum[r] += __shfl_xor(psum[r], off, 64);
#pragma unroll
    for (int r = 0; r < 4; r++) l_r[r] = l_r[r] * al[r] + psum[r];
#pragma unroll
    for (int nv = 0; nv < 8; nv++)
#pragma unroll
      for (int r = 0; r < 4; r++) Oacc[nv][r] *= al[r];
    // P@V (P re-layout through per-wave LDS; same-wave dependency, compiler waits)
    short8 pf[2];
#pragma unroll
    for (int k2 = 0; k2 < 2; k2++) pf[k2] = *(short8*)&Ps[wave * 1152 + lm * 72 + k2 * 32 + lk * 8];
#pragma unroll
    for (int k2 = 0; k2 < 2; k2++)
#pragma unroll
      for (int nv = 0; nv < 8; nv++) {
        short8 vf = *(short8*)&Vs[(nv * 16 + lm) * 72 + k2 * 32 + lk * 8];
        Oacc[nv] = __builtin_amdgcn_mfma_f32_16x16x32_bf16(pf[k2], vf, Oacc[nv], 0, 0, 0);
      }
  }
  float invl[4];
#pragma unroll
  for (int r = 0; r < 4; r++) invl[r] = 1.0f / l_r[r];
#pragma unroll
  for (int nv = 0; nv < 8; nv++)
#pragma unroll
    for (int r = 0; r < 4; r++) {
      int t_row = qbase + wave * 16 + lk * 4 + r;
      o[((size_t)t_row * kH + h) * kVD + nv * 16 + lm] = Oacc[nv][r] * invl[r];
    }
}

// ---------------- f32 kernels ----------------

__global__ __launch_bounds__(256) void k_add_rms(const float* __restrict__ h, const float* __restrict__ r,
                                                 const float* __restrict__ w, float* __restrict__ resid,
                                                 float* __restrict__ out) {
  __shared__ float row[kD];
  __shared__ float red[4];
  int t = blockIdx.x;
  size_t base = (size_t)t * kD;
  float ss = 0.f;
  for (int c = threadIdx.x; c < kD; c += 256) {
    float v = h[base + c] + r[base + c];
    row[c] = v; resid[base + c] = v; ss += v * v;
  }
  float tot = bsum256(ss, red);
  float inv = 1.0f / sqrtf(tot * (1.0f / kD) + 1e-6f);
  for (int c = threadIdx.x; c < kD; c += 256) out[base + c] = row[c] * inv * w[c];
}

__global__ __launch_bounds__(256) void k_rms_rows(const float* __restrict__ in, int stride, int off,
                                                  const float* __restrict__ w, float* __restrict__ out, int cols) {
  __shared__ float row[kD];
  __shared__ float red[4];
  int t = blockIdx.x;
  const float* x = in + (size_t)t * stride + off;
  float ss = 0.f;
  for (int c = threadIdx.x; c < cols; c += 256) { float v = x[c]; row[c] = v; ss += v * v; }
  float tot = bsum256(ss, red);
  float inv = 1.0f / sqrtf(tot / (float)cols + 1e-6f);
  for (int c = threadIdx.x; c < cols; c += 256) out[(size_t)t * cols + c] = row[c] * inv * w[c];
}

__global__ __launch_bounds__(256) void k_gemm(const float* __restrict__ A, const float* __restrict__ B,
                                              float* __restrict__ C, int M, int N, int K,
                                              const float* __restrict__ addend) {
  __shared__ float As[16][68];
  __shared__ float Bs[16][68];
  int bm = blockIdx.y * 64, bn = blockIdx.x * 64;
  int tid = threadIdx.x, tx = tid & 15, ty = tid >> 4;
  int tx4 = tx * 4, ty4 = ty * 4;
  int ar = tid >> 2, ak = (tid & 3) << 2;
  int brk = tid >> 4, bn0 = (tid & 15) << 2;
  float acc[4][4] = {};
  for (int k0 = 0; k0 < K; k0 += 16) {
    {
      int gm = bm + ar;
      if (gm < M) {
        const float4 a4 = *(const float4*)&A[(size_t)gm * K + k0 + ak];
        As[ak][ar] = a4.x; As[ak + 1][ar] = a4.y; As[ak + 2][ar] = a4.z; As[ak + 3][ar] = a4.w;
      } else {
        As[ak][ar] = 0.f; As[ak + 1][ar] = 0.f; As[ak + 2][ar] = 0.f; As[ak + 3][ar] = 0.f;
      }
    }
    {
      int gk = k0 + brk;
      int gn = bn + bn0;
      if (gn + 3 < N) {
        const float4 b4 = *(const float4*)&B[(size_t)gk * N + gn];
        Bs[brk][bn0] = b4.x; Bs[brk][bn0 + 1] = b4.y; Bs[brk][bn0 + 2] = b4.z; Bs[brk][bn0 + 3] = b4.w;
      } else {
#pragma unroll
        for (int i = 0; i < 4; i++) Bs[brk][bn0 + i] = (gn + i < N) ? B[(size_t)gk * N + gn + i] : 0.f;
      }
    }
    __syncthreads();
#pragma unroll
    for (int kk = 0; kk < 16; kk++) {
      float a0 = As[kk][ty4], a1 = As[kk][ty4 + 1], a2 = As[kk][ty4 + 2], a3 = As[kk][ty4 + 3];
      float b0 = Bs[kk][tx4], b1 = Bs[kk][tx4 + 1], b2 = Bs[kk][tx4 + 2], b3 = Bs[kk][tx4 + 3];
      acc[0][0] += a0 * b0; acc[0][1] += a0 * b1; acc[0][2] += a0 * b2; acc[0][3] += a0 * b3;
      acc[1][0] += a1 * b0; acc[1][1] += a1 * b1; acc[1][2] += a1 * b2; acc[1][3] += a1 * b3;
      acc[2][0] += a2 * b0; acc[2][1] += a2 * b1; acc[2][2] += a2 * b2; acc[2][3] += a2 * b3;
      acc[3][0] += a3 * b0; acc[3][1] += a3 * b1; acc[3][2] += a3 * b2; acc[3][3] += a3 * b3;
    }
    __syncthreads();
  }
#pragma unroll
  for (int i = 0; i < 4; i++) {
    int gm = bm + ty4 + i;
    if (gm >= M) continue;
#pragma unroll
    for (int j = 0; j < 4; j++) {
      int gn = bn + tx4 + j;
      if (gn >= N) continue;
      float v = acc[i][j];
      if (addend) v += addend[(size_t)gm * N + gn];
      C[(size_t)gm * N + gn] = v;
    }
  }
}

__global__ __launch_bounds__(256) void k_rope_q(float* __restrict__ q, const int* __restrict__ pos) {
  int t = blockIdx.x;
  float p = (float)pos[t];
  for (int idx = threadIdx.x; idx < kH * 32; idx += 256) {
    int h = idx >> 5, j = idx & 31;
    float invf = 1.0f / powf(10000.0f, (float)j * 0.03125f);
    float ang = p * invf; float s, c; sincosf(ang, &s, &c);
    size_t base = ((size_t)t * kH + h) * kQKD + kNOPE + 2 * j;
    float x1 = q[base], x2 = q[base + 1];
    q[base] = x1 * c - x2 * s;
    q[base + 1] = x2 * c + x1 * s;
  }
}

__global__ __launch_bounds__(256) void k_rope_iq(float* __restrict__ iq, const int* __restrict__ pos) {
  int t = blockIdx.x;
  float p = (float)pos[t];
  for (int idx = threadIdx.x; idx < kIH * 32; idx += 256) {
    int h = idx >> 5, j = idx & 31;
    float invf = 1.0f / powf(10000.0f, (float)j * 0.03125f);
    float ang = p * invf; float s, c; sincosf(ang, &s, &c);
    size_t base = ((size_t)t * kIH + h) * kID + 2 * j;
    float x1 = iq[base], x2 = iq[base + 1];
    iq[base] = x1 * c - x2 * s;
    iq[base + 1] = x2 * c + x1 * s;
  }
}

__global__ __launch_bounds__(64) void k_rope_kpe(const float* __restrict__ qkv, const int* __restrict__ pos,
                                                 float* __restrict__ kpe) {
  int t = blockIdx.x; int j = threadIdx.x;
  if (j >= 32) return;
  float p = (float)pos[t];
  float invf = 1.0f / powf(10000.0f, (float)j * 0.03125f);
  float ang = p * invf; float s, c; sincosf(ang, &s, &c);
  const float* src = qkv + (size_t)t * kQKV_N + kQL + kKVL;
  float x1 = src[2 * j], x2 = src[2 * j + 1];
  kpe[(size_t)t * 64 + 2 * j] = x1 * c - x2 * s;
  kpe[(size_t)t * 64 + 2 * j + 1] = x2 * c + x1 * s;
}

__global__ __launch_bounds__(64) void k_quant_rows(float* __restrict__ x, float* __restrict__ scales) {
  int row = blockIdx.x;
  float* p = x + (size_t)row * kID;
  int l = threadIdx.x;
  float v0 = p[2 * l], v1 = p[2 * l + 1];
  float am = wmax64(fmaxf(fabsf(v0), fabsf(v1)));
  float scale = pow2ceil(fmaxf(am / 448.0f, 1e-10f));
  float inv = 1.0f / scale;
  p[2 * l]     = fp8q(fminf(fmaxf(v0 * inv, -448.f), 448.f));
  p[2 * l + 1] = fp8q(fminf(fmaxf(v1 * inv, -448.f), 448.f));
  if (l == 0) scales[row] = scale;
}

__global__ __launch_bounds__(64) void k_ik_process(const float* __restrict__ raw, const float* __restrict__ w,
                                                   const float* __restrict__ b, const int* __restrict__ pos,
                                                   float* __restrict__ outq, float* __restrict__ scales) {
  int t = blockIdx.x; int l = threadIdx.x;
  const float* x = raw + (size_t)t * kID;
  float x0 = x[2 * l], x1 = x[2 * l + 1];
  float mean = wsum(x0 + x1) * (1.0f / 128.0f);
  float d0 = x0 - mean, d1 = x1 - mean;
  float var = wsum(d0 * d0 + d1 * d1) * (1.0f / 128.0f);
  float inv = 1.0f / sqrtf(var + 1e-6f);
  float y0 = d0 * inv * w[2 * l] + b[2 * l];
  float y1 = d1 * inv * w[2 * l + 1] + b[2 * l + 1];
  if (l < 32) {
    float p = (float)pos[t];
    float invf = 1.0f / powf(10000.0f, (float)l * 0.03125f);
    float ang = p * invf; float sn, cs; sincosf(ang, &sn, &cs);
    float r0 = y0 * cs - y1 * sn, r1 = y1 * cs + y0 * sn;
    y0 = r0; y1 = r1;
  }
  float am = wmax64(fmaxf(fabsf(y0), fabsf(y1)));
  float scale = pow2ceil(fmaxf(am / 448.0f, 1e-10f));
  float is = 1.0f / scale;
  outq[(size_t)t * kID + 2 * l]     = fp8q(fminf(fmaxf(y0 * is, -448.f), 448.f));
  outq[(size_t)t * kID + 2 * l + 1] = fp8q(fminf(fmaxf(y1 * is, -448.f), 448.f));
  if (l == 0) scales[t] = scale;
}

__global__ __launch_bounds__(256) void k_iw(const float* __restrict__ raw, const float* __restrict__ sc,
                                            float* __restrict__ out) {
  int i = blockIdx.x * 256 + threadIdx.x;
  if (i < kT * kIH) out[i] = raw[i] * sc[i] * 0.08838834764831845f * 0.17677669529663687f;
}

__global__ __launch_bounds__(256) void k_scores(const float* __restrict__ iq, const float* __restrict__ ik,
                                                const float* __restrict__ iksc, const float* __restrict__ iw,
                                                float* __restrict__ scores) {
  __shared__ __align__(16) float iqs[kIH * kID];
  __shared__ float iws[kIH];
  int t = blockIdx.x;
  for (int i = threadIdx.x; i < kIH * kID; i += 256) iqs[i] = iq[(size_t)t * kIH * kID + i];
  if (threadIdx.x < kIH) iws[threadIdx.x] = iw[t * kIH + threadIdx.x];
  __syncthreads();
  for (int s = threadIdx.x; s <= t; s += 256) {
    float acc[kIH];
#pragma unroll
    for (int h = 0; h < kIH; h++) acc[h] = 0.f;
    const float4* kr = (const float4*)(ik + (size_t)s * kID);
    for (int d4 = 0; d4 < kID / 4; d4++) {
      float4 kv4 = kr[d4];
#pragma unroll
      for (int h = 0; h < kIH; h++) {
        const float4 q4 = *(const float4*)&iqs[h * kID + d4 * 4];
        acc[h] += q4.x * kv4.x + q4.y * kv4.y + q4.z * kv4.z + q4.w * kv4.w;
      }
    }
    float scv = iksc[s];
    float tot = 0.f;
#pragma unroll
    for (int h = 0; h < kIH; h++) tot += iws[h] * fmaxf(acc[h] * scv, 0.f);
    scores[(size_t)t * kT + s] = tot;
  }
}

// exact top-256 -> bit-packed mask (u64 x16 per row), causal&sel combined
__global__ __launch_bounds__(64) void k_topk(const float* __restrict__ scores, unsigned long long* __restrict__ mbits) {
  int t = blockIdx.x; int l = threadIdx.x;
  __shared__ unsigned short tmp[64];
  unsigned long long* mrow = mbits + (size_t)t * 16;
  if (t < kTOPK) {
    if (l < 16) {
      int lo = l * 64, hi = lo + 63;
      unsigned long long bits;
      if (hi <= t) bits = ~0ull;
      else if (lo > t) bits = 0ull;
      else bits = (1ull << (t - lo + 1)) - 1ull;
      mrow[l] = bits;
    }
    return;
  }
  unsigned key[16];
  const float* srow = scores + (size_t)t * kT;
#pragma unroll
  for (int i = 0; i < 16; i++) {
    int s = l * 16 + i;
    key[i] = (s <= t) ? sortkey(srow[s]) : 0u;
  }
  unsigned prefix = 0; int remaining = kTOPK;
  for (int bit = 31; bit >= 0; bit--) {
    unsigned himask = 0xFFFFFFFFu << bit;
    unsigned cmp = prefix | (1u << bit);
    int c = 0;
#pragma unroll
    for (int i = 0; i < 16; i++) c += ((key[i] & himask) == cmp) ? 1 : 0;
    c = wsum_i(c);
    if (c >= remaining) prefix = cmp; else remaining -= c;
  }
  int ceq = 0, cgt = 0;
#pragma unroll
  for (int i = 0; i < 16; i++) { ceq += (key[i] == prefix) ? 1 : 0; cgt += (key[i] > prefix) ? 1 : 0; }
  int v = ceq;
#pragma unroll
  for (int o = 1; o < 64; o <<= 1) { int u = __shfl_up(v, o, 64); if (l >= o) v += u; }
  int rank = v - ceq;
  int need = kTOPK - wsum_i(cgt);
  unsigned short mybits = 0;
#pragma unroll
  for (int i = 0; i < 16; i++) {
    int sel;
    if (key[i] > prefix) sel = 1;
    else if (key[i] == prefix) { sel = (rank < need) ? 1 : 0; rank++; }
    else sel = 0;
    mybits |= (unsigned short)(sel << i);
  }
  tmp[l] = mybits;
  __syncthreads();
  if (l < 16) {
    mrow[l] = (unsigned long long)tmp[4 * l] | ((unsigned long long)tmp[4 * l + 1] << 16) |
              ((unsigned long long)tmp[4 * l + 2] << 32) | ((unsigned long long)tmp[4 * l + 3] << 48);
  }
}

__global__ __launch_bounds__(64) void k_route(const float* __restrict__ hs2, const float* __restrict__ wg,
                                              int* __restrict__ cnt, int* __restrict__ toki,
                                              float* __restrict__ tokw) {
  int t = blockIdx.x; int l = threadIdx.x;
  float acc[8] = {};
  for (int d = l; d < kD; d += 64) {
    float hv = hs2[(size_t)t * kD + d];
    const float* wr = wg + (size_t)d * 8;
#pragma unroll
    for (int e = 0; e < 8; e++) acc[e] += hv * wr[e];
  }
#pragma unroll
  for (int e = 0; e < 8; e++) acc[e] = wsum(acc[e]);
  if (l == 0) {
    float g[8];
#pragma unroll
    for (int e = 0; e < 8; e++) g[e] = 1.0f / (1.0f + expf(-acc[e]));
    int i0 = 0;
    for (int e = 1; e < 8; e++) if (g[e] > g[i0]) i0 = e;
    int i1 = (i0 == 0) ? 1 : 0;
    for (int e = 0; e < 8; e++) if (e != i0 && g[e] > g[i1]) i1 = e;
    float ssum = g[i0] + g[i1];
    float w0 = g[i0] / ssum * 2.5f, w1 = g[i1] / ssum * 2.5f;
    int s0 = atomicAdd(&cnt[i0], 1); toki[i0 * kT + s0] = t; tokw[i0 * kT + s0] = w0;
    int s1 = atomicAdd(&cnt[i1], 1); toki[i1 * kT + s1] = t; tokw[i1 * kT + s1] = w1;
  }
}

// ---------------- launch ----------------
extern "C" void kernel_launch(void* const* d_in, const int* in_sizes, int n_in,
                              void* d_out, int out_size, void* d_ws, size_t ws_size,
                              hipStream_t stream) {
  (void)in_sizes; (void)n_in; (void)out_size; (void)ws_size;
  const int*   positions  = (const int*)d_in[0];
  const float* hidden     = (const float*)d_in[1];
  const float* residual   = (const float*)d_in[2];
  const float* input_ln_w = (const float*)d_in[3];
  const float* post_ln_w  = (const float*)d_in[4];
  const float* w_qkv_a    = (const float*)d_in[5];
  const float* q_a_ln_w   = (const float*)d_in[6];
  const float* w_q_b      = (const float*)d_in[7];
  const float* kv_a_ln_w  = (const float*)d_in[8];
  const float* w_kv_b     = (const float*)d_in[9];
  const float* w_o        = (const float*)d_in[10];
  const float* w_idx_q_b  = (const float*)d_in[11];
  const float* w_idx_k    = (const float*)d_in[12];
  const float* idx_k_ln_w = (const float*)d_in[13];
  const float* idx_k_ln_b = (const float*)d_in[14];
  const float* w_idx_w    = (const float*)d_in[15];
  const float* w_gate     = (const float*)d_in[16];
  const float* w_moe_gate = (const float*)d_in[17];
  const float* w_moe_up   = (const float*)d_in[18];
  const float* w_moe_down = (const float*)d_in[19];
  const float* w_sh_gate  = (const float*)d_in[20];
  const float* w_sh_up    = (const float*)d_in[21];
  const float* w_sh_down  = (const float*)d_in[22];

  float* out0 = (float*)d_out;
  float* out1 = out0 + (size_t)kT * kD;

  float* W = (float*)d_ws;
  size_t off = 0;
  auto alloc = [&](size_t nfl) { float* p = W + off; off += nfl; return p; };
  float* resid   = alloc((size_t)kT * kD);
  float* hs      = alloc((size_t)kT * kD);
  float* qkv     = alloc((size_t)kT * kQKV_N);
  float* q_c     = alloc((size_t)kT * kQL);
  float* kv_cn   = alloc((size_t)kT * kKVL);
  float* qb      = alloc((size_t)kT * kH * kQKD);
  float* kvb     = alloc((size_t)kT * kH * 256);
  float* iqb     = alloc((size_t)kT * kIH * kID);
  float* ikraw   = alloc((size_t)kT * kID);
  float* ikb     = alloc((size_t)kT * kID);
  float* iksc    = alloc(kT);
  float* iqsc    = alloc((size_t)kT * kIH);
  float* iwraw   = alloc((size_t)kT * kIH);
  float* iwb     = alloc((size_t)kT * kIH);
  float* kpe     = alloc((size_t)kT * kROPE);
  float* scoresb = alloc((size_t)kT * kT);
  unsigned long long* mbits = (unsigned long long*)alloc((size_t)kT * 32);
  float* o_attn  = alloc((size_t)kT * kH * kVD);
  float* hs2     = alloc((size_t)kT * kD);
  float* sg      = alloc((size_t)kT * kF);
  float* hmid    = alloc((size_t)kE * kT * kF);
  float* tokw    = alloc((size_t)kE * kT);
  int*   toki    = (int*)alloc((size_t)kE * kT);
  int*   cnt     = (int*)alloc(16);

  k_add_rms<<<kT, 256, 0, stream>>>(hidden, residual, input_ln_w, resid, hs);
  // qkv_a + index path stay f32 (protect fp8/topk selection from bf16 drift)
  { dim3 g((kQKV_N + 63) / 64, kT / 64); k_gemm<<<g, 256, 0, stream>>>(hs, w_qkv_a, qkv, kT, kQKV_N, kD, nullptr); }
  k_rms_rows<<<kT, 256, 0, stream>>>(qkv, kQKV_N, 0, q_a_ln_w, q_c, kQL);
  k_rms_rows<<<kT, 256, 0, stream>>>(qkv, kQKV_N, kQL, kv_a_ln_w, kv_cn, kKVL);
  { dim3 g(kH * kQKD / 128, kT / 128); k_gemm_bf16<<<g, 256, 0, stream>>>(q_c, w_q_b, qb, nullptr, kT, kH * kQKD, kQL); }
  { dim3 g((kIH * kID) / 64, kT / 64); k_gemm<<<g, 256, 0, stream>>>(q_c, w_idx_q_b, iqb, kT, kIH * kID, kQL, nullptr); }
  { dim3 g(kH * 256 / 128, kT / 128); k_gemm_bf16<<<g, 256, 0, stream>>>(kv_cn, w_kv_b, kvb, nullptr, kT, kH * 256, kKVL); }
  { dim3 g(2, kT / 64); k_gemm<<<g, 256, 0, stream>>>(hs, w_idx_k, ikraw, kT, kID, kD, nullptr); }
  { dim3 g(1, kT / 64); k_gemm<<<g, 256, 0, stream>>>(hs, w_idx_w, iwraw, kT, kIH, kD, nullptr); }
  k_rope_q<<<kT, 256, 0, stream>>>(qb, positions);
  k_rope_iq<<<kT, 256, 0, stream>>>(iqb, positions);
  k_rope_kpe<<<kT, 64, 0, stream>>>(qkv, positions, kpe);
  k_quant_rows<<<kT * kIH, 64, 0, stream>>>(iqb, iqsc);
  k_ik_process<<<kT, 64, 0, stream>>>(ikraw, idx_k_ln_w, idx_k_ln_b, positions, ikb, iksc);
  k_iw<<<(kT * kIH + 255) / 256, 256, 0, stream>>>(iwraw, iqsc, iwb);
  k_scores<<<kT, 256, 0, stream>>>(iqb, ikb, iksc, iwb, scoresb);
  k_topk<<<kT, 64, 0, stream>>>(scoresb, mbits);
  { dim3 g(kT / 64, kH); k_attn_mfma<<<g, 256, 0, stream>>>(qb, kvb, kpe, mbits, o_attn); }
  { dim3 g(kD / 128, kT / 128); k_gemm_bf16<<<g, 256, 0, stream>>>(o_attn, w_o, out1, resid, kT, kD, kH * kVD); }
  k_rms_rows<<<kT, 256, 0, stream>>>(out1, kD, 0, post_ln_w, hs2, kD);
  hipMemsetAsync(cnt, 0, 8 * sizeof(int), stream);
  k_route<<<kT, 64, 0, stream>>>(hs2, w_gate, cnt, toki, tokw);
  { dim3 g(kF / 128, kT / 128, 1); k_dual_bf16<<<g, 256, 0, stream>>>(hs2, w_sh_gate, w_sh_up, sg, nullptr, nullptr, kT, kF, kD); }
  { dim3 g(kD / 128, kT / 128); k_gemm_bf16<<<g, 256, 0, stream>>>(sg, w_sh_down, out0, nullptr, kT, kD, kF); }
  { dim3 g(kF / 128, kT / 128, kE); k_dual_bf16<<<g, 256, 0, stream>>>(hs2, w_moe_gate, w_moe_up, hmid, toki, cnt, kT, kF, kD); }
  { dim3 g(kD / 128, kT / 128, kE); k_down_bf16<<<g, 256, 0, stream>>>(hmid, w_moe_down, toki, tokw, cnt, out0); }
}

// Round 4
// 1414.049 us; speedup vs baseline: 2.5854x; 1.3309x over previous
//
#include <hip/hip_runtime.h>

namespace {
constexpr int kT = 1024, kD = 2048, kH = 16, kNOPE = 128, kROPE = 64, kVD = 128, kQKD = 192;
constexpr int kQL = 768, kKVL = 512, kIH = 32, kID = 128, kTOPK = 256, kE = 8, kF = 1024;
constexpr int kQKV_N = kQL + kKVL + kROPE; // 1344
constexpr int kQKV_NP = 1408;              // padded to 128
}

typedef __attribute__((ext_vector_type(4))) float floatx4;
typedef __attribute__((ext_vector_type(8))) short short8;
typedef unsigned short u16;

// ---------------- device helpers ----------------
__device__ __forceinline__ float wsum(float v) {
#pragma unroll
  for (int o = 32; o; o >>= 1) v += __shfl_xor(v, o, 64);
  return v;
}
__device__ __forceinline__ float wmax64(float v) {
#pragma unroll
  for (int o = 32; o; o >>= 1) v = fmaxf(v, __shfl_xor(v, o, 64));
  return v;
}
__device__ __forceinline__ int wsum_i(int v) {
#pragma unroll
  for (int o = 32; o; o >>= 1) v += __shfl_xor(v, o, 64);
  return v;
}
__device__ __forceinline__ float bsum256(float v, float* red) {
  v = wsum(v);
  if ((threadIdx.x & 63) == 0) red[threadIdx.x >> 6] = v;
  __syncthreads();
  float t = red[0] + red[1] + red[2] + red[3];
  __syncthreads();
  return t;
}
__device__ __forceinline__ unsigned sortkey(float f) {
  unsigned b = __float_as_uint(f);
  return (b & 0x80000000u) ? ~b : (b | 0x80000000u);
}
__device__ __forceinline__ float pow2ceil(float z) {
  unsigned b = __float_as_uint(z);
  if ((b & 0x7FFFFFu) == 0) return z;
  return __uint_as_float((((b >> 23) & 0xFFu) + 1u) << 23);
}
__device__ __forceinline__ float fp8q(float x) {
  float ax = fabsf(x);
  float q;
  if (ax < 0.015625f) {
    q = rintf(ax * 512.0f) * 0.001953125f;
  } else {
    unsigned b = __float_as_uint(ax);
    int e = (int)((b >> 23) & 0xFF) - 127;
    float quant = __uint_as_float((unsigned)(e - 3 + 127) << 23);
    float rq    = __uint_as_float((unsigned)(127 - (e - 3)) << 23);
    q = rintf(ax * rq) * quant;
  }
  return copysignf(q, x);
}
__device__ __forceinline__ u16 f2bf(float x) {
  unsigned u = __float_as_uint(x);
  u += 0x7FFFu + ((u >> 16) & 1u);
  return (u16)(u >> 16);
}
__device__ __forceinline__ float bf2f(u16 h) { return __uint_as_float((unsigned)h << 16); }

// async global->LDS, 16B per lane; lds ptr must be wave-uniform (HW adds lane*16)
__device__ __forceinline__ void gld_lds16(const void* g, void* l) {
  __builtin_amdgcn_global_load_lds(
      (const __attribute__((address_space(1))) unsigned int*)(unsigned long long)g,
      (__attribute__((address_space(3))) unsigned int*)(unsigned int)(unsigned long long)l,
      16, 0, 0);
}
// stage 128 rows x 32 bf16 cols; wave stages rows [wave*32, wave*32+32)
__device__ __forceinline__ void stage_tile(const u16* g, size_t strideUs, u16* tile, int wave, int lane) {
  int r = lane >> 2, c = lane & 3;
  const u16* gp = g + (size_t)(wave * 32 + r) * strideUs + c * 8;
  gld_lds16(gp, tile + (wave * 32) * 32);
  gld_lds16(gp + (size_t)16 * strideUs, tile + (wave * 32 + 16) * 32);
}

// ---------------- weight prep: f32 [K][N] -> bf16 BT [Npad][K] (+optional lo) ----------------
__global__ __launch_bounds__(256) void k_transpose_w(const float* __restrict__ in, u16* __restrict__ hi,
                                                     u16* __restrict__ lo, int K, int N, int Npad) {
  __shared__ float tile[32][33];
  int n0 = blockIdx.x * 32, k0 = blockIdx.y * 32;
  const float* ip = in + (size_t)blockIdx.z * K * N;
  u16* hp = hi + (size_t)blockIdx.z * Npad * K;
  u16* lp = lo ? lo + (size_t)blockIdx.z * Npad * K : nullptr;
  int t = threadIdx.x;
  int r = t >> 3, c4 = (t & 7) << 2;
  if (n0 < N) {
    float4 v = *(const float4*)&ip[(size_t)(k0 + r) * N + n0 + c4];
    tile[r][c4] = v.x; tile[r][c4 + 1] = v.y; tile[r][c4 + 2] = v.z; tile[r][c4 + 3] = v.w;
  } else {
    tile[r][c4] = 0.f; tile[r][c4 + 1] = 0.f; tile[r][c4 + 2] = 0.f; tile[r][c4 + 3] = 0.f;
  }
  __syncthreads();
  int n = t >> 3, kq = (t & 7) << 2;
  ushort4 h4, l4;
#pragma unroll
  for (int j = 0; j < 4; j++) {
    float f = tile[kq + j][n];
    u16 h = f2bf(f);
    ((u16*)&h4)[j] = h;
    ((u16*)&l4)[j] = f2bf(f - bf2f(h));
  }
  *(ushort4*)&hp[(size_t)(n0 + n) * K + k0 + kq] = h4;
  if (lp) *(ushort4*)&lp[(size_t)(n0 + n) * K + k0 + kq] = l4;
}

// ---------------- GEMM family: bf16 A [M][K], bf16 BT [N][K], global_load_lds staging ----------
// 128x128 tile, BK=32, 4 waves in 2x2 quadrants.

__global__ __launch_bounds__(256) void k_gemm_bt(const u16* __restrict__ A, const u16* __restrict__ BT,
                                                 float* __restrict__ C, const float* __restrict__ addend,
                                                 int M, int N, int K) {
  __shared__ __align__(16) u16 As[128 * 32];
  __shared__ __align__(16) u16 Bs[128 * 32];
  int tid = threadIdx.x, wave = tid >> 6, lane = tid & 63;
  int bm = blockIdx.y * 128, bn = blockIdx.x * 128;
  int wy = (wave >> 1) * 64, wx = (wave & 1) * 64;
  int lm = lane & 15, lk = lane >> 4;
  const u16* Ab = A + (size_t)bm * K;
  const u16* Bb = BT + (size_t)bn * K;
  floatx4 acc[4][4] = {};
  for (int k0 = 0; k0 < K; k0 += 32) {
    stage_tile(Ab + k0, K, As, wave, lane);
    stage_tile(Bb + k0, K, Bs, wave, lane);
    __syncthreads();
    short8 af[4], bfr[4];
#pragma unroll
    for (int mt = 0; mt < 4; mt++) af[mt] = *(short8*)&As[(wy + mt * 16 + lm) * 32 + lk * 8];
#pragma unroll
    for (int nt = 0; nt < 4; nt++) bfr[nt] = *(short8*)&Bs[(wx + nt * 16 + lm) * 32 + lk * 8];
#pragma unroll
    for (int mt = 0; mt < 4; mt++)
#pragma unroll
      for (int nt = 0; nt < 4; nt++)
        acc[mt][nt] = __builtin_amdgcn_mfma_f32_16x16x32_bf16(af[mt], bfr[nt], acc[mt][nt], 0, 0, 0);
    __syncthreads();
  }
#pragma unroll
  for (int mt = 0; mt < 4; mt++)
#pragma unroll
    for (int nt = 0; nt < 4; nt++)
#pragma unroll
      for (int r = 0; r < 4; r++) {
        int m = bm + wy + mt * 16 + lk * 4 + r;
        int n = bn + wx + nt * 16 + lm;
        float v = acc[mt][nt][r];
        if (addend) v += addend[(size_t)m * N + n];
        C[(size_t)m * N + n] = v;
      }
}

// 3-term split-precision GEMM: C = Ahi*Bhi + Ahi*Blo + Alo*Bhi (f32-class accuracy).
// N may be < padded BT rows; C guarded & strided by N.
__global__ __launch_bounds__(256) void k_gemm_split(const u16* __restrict__ Ah, const u16* __restrict__ Al,
                                                    const u16* __restrict__ Bh, const u16* __restrict__ Bl,
                                                    float* __restrict__ C, int M, int N, int K) {
  __shared__ __align__(16) u16 Ahs[128 * 32];
  __shared__ __align__(16) u16 Als[128 * 32];
  __shared__ __align__(16) u16 Bhs[128 * 32];
  __shared__ __align__(16) u16 Bls[128 * 32];
  int tid = threadIdx.x, wave = tid >> 6, lane = tid & 63;
  int bm = blockIdx.y * 128, bn = blockIdx.x * 128;
  int wy = (wave >> 1) * 64, wx = (wave & 1) * 64;
  int lm = lane & 15, lk = lane >> 4;
  floatx4 acc[4][4] = {};
  for (int k0 = 0; k0 < K; k0 += 32) {
    stage_tile(Ah + (size_t)bm * K + k0, K, Ahs, wave, lane);
    stage_tile(Al + (size_t)bm * K + k0, K, Als, wave, lane);
    stage_tile(Bh + (size_t)bn * K + k0, K, Bhs, wave, lane);
    stage_tile(Bl + (size_t)bn * K + k0, K, Bls, wave, lane);
    __syncthreads();
    short8 ah[4], al[4], bh[4], bl[4];
#pragma unroll
    for (int mt = 0; mt < 4; mt++) { ah[mt] = *(short8*)&Ahs[(wy + mt * 16 + lm) * 32 + lk * 8];
                                     al[mt] = *(short8*)&Als[(wy + mt * 16 + lm) * 32 + lk * 8]; }
#pragma unroll
    for (int nt = 0; nt < 4; nt++) { bh[nt] = *(short8*)&Bhs[(wx + nt * 16 + lm) * 32 + lk * 8];
                                     bl[nt] = *(short8*)&Bls[(wx + nt * 16 + lm) * 32 + lk * 8]; }
#pragma unroll
    for (int mt = 0; mt < 4; mt++)
#pragma unroll
      for (int nt = 0; nt < 4; nt++) {
        floatx4 a = acc[mt][nt];
        a = __builtin_amdgcn_mfma_f32_16x16x32_bf16(al[mt], bh[nt], a, 0, 0, 0);
        a = __builtin_amdgcn_mfma_f32_16x16x32_bf16(ah[mt], bl[nt], a, 0, 0, 0);
        a = __builtin_amdgcn_mfma_f32_16x16x32_bf16(ah[mt], bh[nt], a, 0, 0, 0);
        acc[mt][nt] = a;
      }
    __syncthreads();
  }
#pragma unroll
  for (int mt = 0; mt < 4; mt++)
#pragma unroll
    for (int nt = 0; nt < 4; nt++)
#pragma unroll
      for (int r = 0; r < 4; r++) {
        int m = bm + wy + mt * 16 + lk * 4 + r;
        int n = bn + wx + nt * 16 + lm;
        if (n < N) C[(size_t)m * N + n] = acc[mt][nt][r];
      }
}

// dual-B gate+up with silu epilogue -> bf16 out; optional row gather (MoE), z = expert
__global__ __launch_bounds__(256) void k_dual_bt(const u16* __restrict__ A, const u16* __restrict__ GT,
                                                 const u16* __restrict__ UT, u16* __restrict__ out,
                                                 const int* __restrict__ toki, const int* __restrict__ cnt,
                                                 int M, int N, int K) {
  int e = blockIdx.z;
  int n_rows = toki ? cnt[e] : M;
  int bm = blockIdx.y * 128;
  if (bm >= n_rows) return;
  int bn = blockIdx.x * 128;
  const int* tk = toki ? (toki + e * kT) : nullptr;
  const u16* Gb = GT + (size_t)e * N * K + (size_t)bn * K;
  const u16* Ub = UT + (size_t)e * N * K + (size_t)bn * K;
  u16* oP = out + (size_t)e * kT * N;
  __shared__ __align__(16) u16 As[128 * 32];
  __shared__ __align__(16) u16 Gs[128 * 32];
  __shared__ __align__(16) u16 Us[128 * 32];
  int tid = threadIdx.x, wave = tid >> 6, lane = tid & 63;
  int wy = (wave >> 1) * 64, wx = (wave & 1) * 64;
  int lm = lane & 15, lk = lane >> 4;
  int r = lane >> 2, c = lane & 3;
  int r0 = bm + wave * 32 + r, r1 = r0 + 16;
  size_t arow0 = tk ? (size_t)((r0 < n_rows) ? tk[r0] : 0) : (size_t)r0;
  size_t arow1 = tk ? (size_t)((r1 < n_rows) ? tk[r1] : 0) : (size_t)r1;
  floatx4 ag[4][4] = {}, au[4][4] = {};
  for (int k0 = 0; k0 < K; k0 += 32) {
    gld_lds16(A + arow0 * K + k0 + c * 8, As + (wave * 32) * 32);
    gld_lds16(A + arow1 * K + k0 + c * 8, As + (wave * 32 + 16) * 32);
    stage_tile(Gb + k0, K, Gs, wave, lane);
    stage_tile(Ub + k0, K, Us, wave, lane);
    __syncthreads();
    short8 af[4], gf[4], uf[4];
#pragma unroll
    for (int mt = 0; mt < 4; mt++) af[mt] = *(short8*)&As[(wy + mt * 16 + lm) * 32 + lk * 8];
#pragma unroll
    for (int nt = 0; nt < 4; nt++) { gf[nt] = *(short8*)&Gs[(wx + nt * 16 + lm) * 32 + lk * 8];
                                     uf[nt] = *(short8*)&Us[(wx + nt * 16 + lm) * 32 + lk * 8]; }
#pragma unroll
    for (int mt = 0; mt < 4; mt++)
#pragma unroll
      for (int nt = 0; nt < 4; nt++) {
        ag[mt][nt] = __builtin_amdgcn_mfma_f32_16x16x32_bf16(af[mt], gf[nt], ag[mt][nt], 0, 0, 0);
        au[mt][nt] = __builtin_amdgcn_mfma_f32_16x16x32_bf16(af[mt], uf[nt], au[mt][nt], 0, 0, 0);
      }
    __syncthreads();
  }
#pragma unroll
  for (int mt = 0; mt < 4; mt++)
#pragma unroll
    for (int nt = 0; nt < 4; nt++)
#pragma unroll
      for (int r2 = 0; r2 < 4; r2++) {
        int gm = bm + wy + mt * 16 + lk * 4 + r2;
        if (gm >= n_rows) continue;
        int n = bn + wx + nt * 16 + lm;
        float gv = ag[mt][nt][r2], uv = au[mt][nt][r2];
        oP[(size_t)gm * N + n] = f2bf(gv * (1.0f / (1.0f + expf(-gv))) * uv);
      }
}

// down: out[tok] += w * (hmid[e] @ wd[e]); A compact bf16 per expert; atomic scatter f32
__global__ __launch_bounds__(256) void k_down_bt(const u16* __restrict__ hmid, const u16* __restrict__ DT,
                                                 const int* __restrict__ toki, const float* __restrict__ tokw,
                                                 const int* __restrict__ cnt, float* __restrict__ out) {
  int e = blockIdx.z;
  int n_rows = cnt[e];
  int bm = blockIdx.y * 128;
  if (bm >= n_rows) return;
  int bn = blockIdx.x * 128;
  const u16* Ab = hmid + (size_t)e * kT * kF + (size_t)bm * kF;
  const u16* Bb = DT + (size_t)e * kD * kF + (size_t)bn * kF;
  __shared__ __align__(16) u16 As[128 * 32];
  __shared__ __align__(16) u16 Bs[128 * 32];
  int tid = threadIdx.x, wave = tid >> 6, lane = tid & 63;
  int wy = (wave >> 1) * 64, wx = (wave & 1) * 64;
  int lm = lane & 15, lk = lane >> 4;
  floatx4 acc[4][4] = {};
  for (int k0 = 0; k0 < kF; k0 += 32) {
    stage_tile(Ab + k0, kF, As, wave, lane);
    stage_tile(Bb + k0, kF, Bs, wave, lane);
    __syncthreads();
    short8 af[4], bfr[4];
#pragma unroll
    for (int mt = 0; mt < 4; mt++) af[mt] = *(short8*)&As[(wy + mt * 16 + lm) * 32 + lk * 8];
#pragma unroll
    for (int nt = 0; nt < 4; nt++) bfr[nt] = *(short8*)&Bs[(wx + nt * 16 + lm) * 32 + lk * 8];
#pragma unroll
    for (int mt = 0; mt < 4; mt++)
#pragma unroll
      for (int nt = 0; nt < 4; nt++)
        acc[mt][nt] = __builtin_amdgcn_mfma_f32_16x16x32_bf16(af[mt], bfr[nt], acc[mt][nt], 0, 0, 0);
    __syncthreads();
  }
#pragma unroll
  for (int mt = 0; mt < 4; mt++)
#pragma unroll
    for (int r = 0; r < 4; r++) {
      int gm = bm + wy + mt * 16 + lk * 4 + r;
      if (gm >= n_rows) continue;
      int tt = toki[e * kT + gm];
      float w = tokw[e * kT + gm];
#pragma unroll
      for (int nt = 0; nt < 4; nt++) {
        int n = bn + wx + nt * 16 + lm;
        atomicAdd(&out[(size_t)tt * kD + n], w * acc[mt][nt][r]);
      }
    }
}

// ---------------- flash MFMA attention (bf16 out) ----------------
__global__ __launch_bounds__(256) void k_attn_mfma(const float* __restrict__ q, const float* __restrict__ kv,
                                                   const float* __restrict__ kpe,
                                                   const unsigned long long* __restrict__ mbits,
                                                   u16* __restrict__ o) {
  __shared__ __align__(16) u16 Ks[64 * 200];
  __shared__ __align__(16) u16 Vs[128 * 72];
  __shared__ __align__(16) u16 Ps[4 * 16 * 72];
  int h = blockIdx.y;
  int qb = gridDim.x - 1 - blockIdx.x;
  int qbase = qb * 64;
  int tid = threadIdx.x;
  int wave = tid >> 6, lane = tid & 63;
  int lm = lane & 15, lk = lane >> 4;
  short8 qf[6];
  {
    const float* qrow = q + ((size_t)(qbase + wave * 16 + lm) * kH + h) * kQKD;
#pragma unroll
    for (int ks = 0; ks < 6; ks++) {
      const float4 a0 = *(const float4*)&qrow[ks * 32 + lk * 8];
      const float4 a1 = *(const float4*)&qrow[ks * 32 + lk * 8 + 4];
      short8 f;
      f[0] = (short)f2bf(a0.x); f[1] = (short)f2bf(a0.y); f[2] = (short)f2bf(a0.z); f[3] = (short)f2bf(a0.w);
      f[4] = (short)f2bf(a1.x); f[5] = (short)f2bf(a1.y); f[6] = (short)f2bf(a1.z); f[7] = (short)f2bf(a1.w);
      qf[ks] = f;
    }
  }
  float m_r[4] = {-1e30f, -1e30f, -1e30f, -1e30f};
  float l_r[4] = {};
  floatx4 Oacc[8] = {};
  int sr = tid >> 2, sj = tid & 3;
  int nch = qb + 1;
  for (int ch = 0; ch < nch; ch++) {
    int s0 = ch << 6;
    __syncthreads();
    {
      const float* kvrow = kv + ((size_t)(s0 + sr) * kH + h) * 256;
      const float* kprow = kpe + (size_t)(s0 + sr) * 64;
#pragma unroll
      for (int i = 0; i < 12; i++) {
        int c4 = (i << 2) + sj;
        float4 v4 = (c4 < 32) ? *(const float4*)&kvrow[c4 * 4] : *(const float4*)&kprow[(c4 - 32) * 4];
        ushort4 p; p.x = f2bf(v4.x); p.y = f2bf(v4.y); p.z = f2bf(v4.z); p.w = f2bf(v4.w);
        *(ushort4*)&Ks[sr * 200 + c4 * 4] = p;
      }
      const float* vrow = kvrow + 128;
#pragma unroll
      for (int i = 0; i < 8; i++) {
        int c4 = (i << 2) + sj;
        float4 v4 = *(const float4*)&vrow[c4 * 4];
        Vs[(c4 * 4 + 0) * 72 + sr] = f2bf(v4.x);
        Vs[(c4 * 4 + 1) * 72 + sr] = f2bf(v4.y);
        Vs[(c4 * 4 + 2) * 72 + sr] = f2bf(v4.z);
        Vs[(c4 * 4 + 3) * 72 + sr] = f2bf(v4.w);
      }
    }
    __syncthreads();
    floatx4 sacc[4] = {};
#pragma unroll
    for (int ks = 0; ks < 6; ks++) {
      short8 kf[4];
#pragma unroll
      for (int nt = 0; nt < 4; nt++) kf[nt] = *(short8*)&Ks[(nt * 16 + lm) * 200 + ks * 32 + lk * 8];
#pragma unroll
      for (int nt = 0; nt < 4; nt++)
        sacc[nt] = __builtin_amdgcn_mfma_f32_16x16x32_bf16(qf[ks], kf[nt], sacc[nt], 0, 0, 0);
    }
    unsigned long long mw[4];
#pragma unroll
    for (int r = 0; r < 4; r++) mw[r] = mbits[(size_t)(qbase + wave * 16 + lk * 4 + r) * 16 + ch];
    float mx[4] = {-1e30f, -1e30f, -1e30f, -1e30f};
#pragma unroll
    for (int nt = 0; nt < 4; nt++)
#pragma unroll
      for (int r = 0; r < 4; r++) {
        int sel = (int)((mw[r] >> (nt * 16 + lm)) & 1ull);
        float sv = sel ? sacc[nt][r] * 0.07216878364870323f : -1e30f;
        sacc[nt][r] = sv;
        mx[r] = fmaxf(mx[r], sv);
      }
#pragma unroll
    for (int off = 1; off < 16; off <<= 1)
#pragma unroll
      for (int r = 0; r < 4; r++) mx[r] = fmaxf(mx[r], __shfl_xor(mx[r], off, 64));
    float al[4], psum[4] = {};
#pragma unroll
    for (int r = 0; r < 4; r++) {
      float mnew = fmaxf(m_r[r], mx[r]);
      al[r] = __expf(m_r[r] - mnew);
      m_r[r] = mnew;
    }
#pragma unroll
    for (int nt = 0; nt < 4; nt++)
#pragma unroll
      for (int r = 0; r < 4; r++) {
        float p = (sacc[nt][r] > -0.9e30f) ? __expf(sacc[nt][r] - m_r[r]) : 0.0f;
        psum[r] += p;
        Ps[wave * 1152 + (lk * 4 + r) * 72 + nt * 16 + lm] = f2bf(p);
      }
#pragma unroll
    for (int off = 1; off < 16; off <<= 1)
#pragma unroll
      for (int r = 0; r < 4; r++) psum[r] += __shfl_xor(psum[r], off, 64);
#pragma unroll
    for (int r = 0; r < 4; r++) l_r[r] = l_r[r] * al[r] + psum[r];
#pragma unroll
    for (int nv = 0; nv < 8; nv++)
#pragma unroll
      for (int r = 0; r < 4; r++) Oacc[nv][r] *= al[r];
    short8 pf[2];
#pragma unroll
    for (int k2 = 0; k2 < 2; k2++) pf[k2] = *(short8*)&Ps[wave * 1152 + lm * 72 + k2 * 32 + lk * 8];
#pragma unroll
    for (int k2 = 0; k2 < 2; k2++)
#pragma unroll
      for (int nv = 0; nv < 8; nv++) {
        short8 vf = *(short8*)&Vs[(nv * 16 + lm) * 72 + k2 * 32 + lk * 8];
        Oacc[nv] = __builtin_amdgcn_mfma_f32_16x16x32_bf16(pf[k2], vf, Oacc[nv], 0, 0, 0);
      }
  }
  float invl[4];
#pragma unroll
  for (int r = 0; r < 4; r++) invl[r] = 1.0f / l_r[r];
#pragma unroll
  for (int nv = 0; nv < 8; nv++)
#pragma unroll
    for (int r = 0; r < 4; r++) {
      int t_row = qbase + wave * 16 + lk * 4 + r;
      o[((size_t)t_row * kH + h) * kVD + nv * 16 + lm] = f2bf(Oacc[nv][r] * invl[r]);
    }
}

// ---------------- norm / small kernels ----------------
__global__ __launch_bounds__(256) void k_add_rms(const float* __restrict__ h, const float* __restrict__ r,
                                                 const float* __restrict__ w, float* __restrict__ resid,
                                                 float* __restrict__ out, u16* __restrict__ oh,
                                                 u16* __restrict__ ol) {
  __shared__ float row[kD];
  __shared__ float red[4];
  int t = blockIdx.x;
  size_t base = (size_t)t * kD;
  float ss = 0.f;
  for (int c = threadIdx.x; c < kD; c += 256) {
    float v = h[base + c] + r[base + c];
    row[c] = v; resid[base + c] = v; ss += v * v;
  }
  float tot = bsum256(ss, red);
  float inv = 1.0f / sqrtf(tot * (1.0f / kD) + 1e-6f);
  for (int c = threadIdx.x; c < kD; c += 256) {
    float v = row[c] * inv * w[c];
    out[base + c] = v;
    u16 hb = f2bf(v);
    oh[base + c] = hb;
    ol[base + c] = f2bf(v - bf2f(hb));
  }
}

// rmsnorm with optional f32 / bf16-hi / bf16-lo outputs
__global__ __launch_bounds__(256) void k_rms_rows(const float* __restrict__ in, int stride, int off,
                                                  const float* __restrict__ w, float* __restrict__ outf,
                                                  u16* __restrict__ oh, u16* __restrict__ ol, int cols) {
  __shared__ float row[kD];
  __shared__ float red[4];
  int t = blockIdx.x;
  const float* x = in + (size_t)t * stride + off;
  float ss = 0.f;
  for (int c = threadIdx.x; c < cols; c += 256) { float v = x[c]; row[c] = v; ss += v * v; }
  float tot = bsum256(ss, red);
  float inv = 1.0f / sqrtf(tot / (float)cols + 1e-6f);
  for (int c = threadIdx.x; c < cols; c += 256) {
    float v = row[c] * inv * w[c];
    if (outf) outf[(size_t)t * cols + c] = v;
    if (oh) {
      u16 hb = f2bf(v);
      oh[(size_t)t * cols + c] = hb;
      if (ol) ol[(size_t)t * cols + c] = f2bf(v - bf2f(hb));
    }
  }
}

// f32 GEMM kept only for the tiny iw matmul (N=32)
__global__ __launch_bounds__(256) void k_gemm(const float* __restrict__ A, const float* __restrict__ B,
                                              float* __restrict__ C, int M, int N, int K,
                                              const float* __restrict__ addend) {
  __shared__ float As[16][68];
  __shared__ float Bs[16][68];
  int bm = blockIdx.y * 64, bn = blockIdx.x * 64;
  int tid = threadIdx.x, tx = tid & 15, ty = tid >> 4;
  int tx4 = tx * 4, ty4 = ty * 4;
  int ar = tid >> 2, ak = (tid & 3) << 2;
  int brk = tid >> 4, bn0 = (tid & 15) << 2;
  float acc[4][4] = {};
  for (int k0 = 0; k0 < K; k0 += 16) {
    {
      int gm = bm + ar;
      if (gm < M) {
        const float4 a4 = *(const float4*)&A[(size_t)gm * K + k0 + ak];
        As[ak][ar] = a4.x; As[ak + 1][ar] = a4.y; As[ak + 2][ar] = a4.z; As[ak + 3][ar] = a4.w;
      } else {
        As[ak][ar] = 0.f; As[ak + 1][ar] = 0.f; As[ak + 2][ar] = 0.f; As[ak + 3][ar] = 0.f;
      }
    }
    {
      int gk = k0 + brk;
      int gn = bn + bn0;
      if (gn + 3 < N) {
        const float4 b4 = *(const float4*)&B[(size_t)gk * N + gn];
        Bs[brk][bn0] = b4.x; Bs[brk][bn0 + 1] = b4.y; Bs[brk][bn0 + 2] = b4.z; Bs[brk][bn0 + 3] = b4.w;
      } else {
#pragma unroll
        for (int i = 0; i < 4; i++) Bs[brk][bn0 + i] = (gn + i < N) ? B[(size_t)gk * N + gn + i] : 0.f;
      }
    }
    __syncthreads();
#pragma unroll
    for (int kk = 0; kk < 16; kk++) {
      float a0 = As[kk][ty4], a1 = As[kk][ty4 + 1], a2 = As[kk][ty4 + 2], a3 = As[kk][ty4 + 3];
      float b0 = Bs[kk][tx4], b1 = Bs[kk][tx4 + 1], b2 = Bs[kk][tx4 + 2], b3 = Bs[kk][tx4 + 3];
      acc[0][0] += a0 * b0; acc[0][1] += a0 * b1; acc[0][2] += a0 * b2; acc[0][3] += a0 * b3;
      acc[1][0] += a1 * b0; acc[1][1] += a1 * b1; acc[1][2] += a1 * b2; acc[1][3] += a1 * b3;
      acc[2][0] += a2 * b0; acc[2][1] += a2 * b1; acc[2][2] += a2 * b2; acc[2][3] += a2 * b3;
      acc[3][0] += a3 * b0; acc[3][1] += a3 * b1; acc[3][2] += a3 * b2; acc[3][3] += a3 * b3;
    }
    __syncthreads();
  }
#pragma unroll
  for (int i = 0; i < 4; i++) {
    int gm = bm + ty4 + i;
    if (gm >= M) continue;
#pragma unroll
    for (int j = 0; j < 4; j++) {
      int gn = bn + tx4 + j;
      if (gn >= N) continue;
      float v = acc[i][j];
      if (addend) v += addend[(size_t)gm * N + gn];
      C[(size_t)gm * N + gn] = v;
    }
  }
}

__global__ __launch_bounds__(256) void k_rope_q(float* __restrict__ q, const int* __restrict__ pos) {
  int t = blockIdx.x;
  float p = (float)pos[t];
  for (int idx = threadIdx.x; idx < kH * 32; idx += 256) {
    int h = idx >> 5, j = idx & 31;
    float invf = 1.0f / powf(10000.0f, (float)j * 0.03125f);
    float ang = p * invf; float s, c; sincosf(ang, &s, &c);
    size_t base = ((size_t)t * kH + h) * kQKD + kNOPE + 2 * j;
    float x1 = q[base], x2 = q[base + 1];
    q[base] = x1 * c - x2 * s;
    q[base + 1] = x2 * c + x1 * s;
  }
}

__global__ __launch_bounds__(256) void k_rope_iq(float* __restrict__ iq, const int* __restrict__ pos) {
  int t = blockIdx.x;
  float p = (float)pos[t];
  for (int idx = threadIdx.x; idx < kIH * 32; idx += 256) {
    int h = idx >> 5, j = idx & 31;
    float invf = 1.0f / powf(10000.0f, (float)j * 0.03125f);
    float ang = p * invf; float s, c; sincosf(ang, &s, &c);
    size_t base = ((size_t)t * kIH + h) * kID + 2 * j;
    float x1 = iq[base], x2 = iq[base + 1];
    iq[base] = x1 * c - x2 * s;
    iq[base + 1] = x2 * c + x1 * s;
  }
}

__global__ __launch_bounds__(64) void k_rope_kpe(const float* __restrict__ qkv, const int* __restrict__ pos,
                                                 float* __restrict__ kpe) {
  int t = blockIdx.x; int j = threadIdx.x;
  if (j >= 32) return;
  float p = (float)pos[t];
  float invf = 1.0f / powf(10000.0f, (float)j * 0.03125f);
  float ang = p * invf; float s, c; sincosf(ang, &s, &c);
  const float* src = qkv + (size_t)t * kQKV_N + kQL + kKVL;
  float x1 = src[2 * j], x2 = src[2 * j + 1];
  kpe[(size_t)t * 64 + 2 * j] = x1 * c - x2 * s;
  kpe[(size_t)t * 64 + 2 * j + 1] = x2 * c + x1 * s;
}

__global__ __launch_bounds__(64) void k_quant_rows(float* __restrict__ x, float* __restrict__ scales) {
  int row = blockIdx.x;
  float* p = x + (size_t)row * kID;
  int l = threadIdx.x;
  float v0 = p[2 * l], v1 = p[2 * l + 1];
  float am = wmax64(fmaxf(fabsf(v0), fabsf(v1)));
  float scale = pow2ceil(fmaxf(am / 448.0f, 1e-10f));
  float inv = 1.0f / scale;
  p[2 * l]     = fp8q(fminf(fmaxf(v0 * inv, -448.f), 448.f));
  p[2 * l + 1] = fp8q(fminf(fmaxf(v1 * inv, -448.f), 448.f));
  if (l == 0) scales[row] = scale;
}

__global__ __launch_bounds__(64) void k_ik_process(const float* __restrict__ raw, const float* __restrict__ w,
                                                   const float* __restrict__ b, const int* __restrict__ pos,
                                                   float* __restrict__ outq, float* __restrict__ scales) {
  int t = blockIdx.x; int l = threadIdx.x;
  const float* x = raw + (size_t)t * kID;
  float x0 = x[2 * l], x1 = x[2 * l + 1];
  float mean = wsum(x0 + x1) * (1.0f / 128.0f);
  float d0 = x0 - mean, d1 = x1 - mean;
  float var = wsum(d0 * d0 + d1 * d1) * (1.0f / 128.0f);
  float inv = 1.0f / sqrtf(var + 1e-6f);
  float y0 = d0 * inv * w[2 * l] + b[2 * l];
  float y1 = d1 * inv * w[2 * l + 1] + b[2 * l + 1];
  if (l < 32) {
    float p = (float)pos[t];
    float invf = 1.0f / powf(10000.0f, (float)l * 0.03125f);
    float ang = p * invf; float sn, cs; sincosf(ang, &sn, &cs);
    float r0 = y0 * cs - y1 * sn, r1 = y1 * cs + y0 * sn;
    y0 = r0; y1 = r1;
  }
  float am = wmax64(fmaxf(fabsf(y0), fabsf(y1)));
  float scale = pow2ceil(fmaxf(am / 448.0f, 1e-10f));
  float is = 1.0f / scale;
  outq[(size_t)t * kID + 2 * l]     = fp8q(fminf(fmaxf(y0 * is, -448.f), 448.f));
  outq[(size_t)t * kID + 2 * l + 1] = fp8q(fminf(fmaxf(y1 * is, -448.f), 448.f));
  if (l == 0) scales[t] = scale;
}

__global__ __launch_bounds__(256) void k_iw(const float* __restrict__ raw, const float* __restrict__ sc,
                                            float* __restrict__ out) {
  int i = blockIdx.x * 256 + threadIdx.x;
  if (i < kT * kIH) out[i] = raw[i] * sc[i] * 0.08838834764831845f * 0.17677669529663687f;
}

__global__ __launch_bounds__(256) void k_scores(const float* __restrict__ iq, const float* __restrict__ ik,
                                                const float* __restrict__ iksc, const float* __restrict__ iw,
                                                float* __restrict__ scores) {
  __shared__ __align__(16) float iqs[kIH * kID];
  __shared__ float iws[kIH];
  int t = blockIdx.x;
  for (int i = threadIdx.x; i < kIH * kID; i += 256) iqs[i] = iq[(size_t)t * kIH * kID + i];
  if (threadIdx.x < kIH) iws[threadIdx.x] = iw[t * kIH + threadIdx.x];
  __syncthreads();
  for (int s = threadIdx.x; s <= t; s += 256) {
    float acc[kIH];
#pragma unroll
    for (int h = 0; h < kIH; h++) acc[h] = 0.f;
    const float4* kr = (const float4*)(ik + (size_t)s * kID);
    for (int d4 = 0; d4 < kID / 4; d4++) {
      float4 kv4 = kr[d4];
#pragma unroll
      for (int h = 0; h < kIH; h++) {
        const float4 q4 = *(const float4*)&iqs[h * kID + d4 * 4];
        acc[h] += q4.x * kv4.x + q4.y * kv4.y + q4.z * kv4.z + q4.w * kv4.w;
      }
    }
    float scv = iksc[s];
    float tot = 0.f;
#pragma unroll
    for (int h = 0; h < kIH; h++) tot += iws[h] * fmaxf(acc[h] * scv, 0.f);
    scores[(size_t)t * kT + s] = tot;
  }
}

__global__ __launch_bounds__(64) void k_topk(const float* __restrict__ scores, unsigned long long* __restrict__ mbits) {
  int t = blockIdx.x; int l = threadIdx.x;
  __shared__ unsigned short tmp[64];
  unsigned long long* mrow = mbits + (size_t)t * 16;
  if (t < kTOPK) {
    if (l < 16) {
      int lo = l * 64, hi = lo + 63;
      unsigned long long bits;
      if (hi <= t) bits = ~0ull;
      else if (lo > t) bits = 0ull;
      else bits = (1ull << (t - lo + 1)) - 1ull;
      mrow[l] = bits;
    }
    return;
  }
  unsigned key[16];
  const float* srow = scores + (size_t)t * kT;
#pragma unroll
  for (int i = 0; i < 16; i++) {
    int s = l * 16 + i;
    key[i] = (s <= t) ? sortkey(srow[s]) : 0u;
  }
  unsigned prefix = 0; int remaining = kTOPK;
  for (int bit = 31; bit >= 0; bit--) {
    unsigned himask = 0xFFFFFFFFu << bit;
    unsigned cmp = prefix | (1u << bit);
    int c = 0;
#pragma unroll
    for (int i = 0; i < 16; i++) c += ((key[i] & himask) == cmp) ? 1 : 0;
    c = wsum_i(c);
    if (c >= remaining) prefix = cmp; else remaining -= c;
  }
  int ceq = 0, cgt = 0;
#pragma unroll
  for (int i = 0; i < 16; i++) { ceq += (key[i] == prefix) ? 1 : 0; cgt += (key[i] > prefix) ? 1 : 0; }
  int v = ceq;
#pragma unroll
  for (int o = 1; o < 64; o <<= 1) { int u = __shfl_up(v, o, 64); if (l >= o) v += u; }
  int rank = v - ceq;
  int need = kTOPK - wsum_i(cgt);
  unsigned short mybits = 0;
#pragma unroll
  for (int i = 0; i < 16; i++) {
    int sel;
    if (key[i] > prefix) sel = 1;
    else if (key[i] == prefix) { sel = (rank < need) ? 1 : 0; rank++; }
    else sel = 0;
    mybits |= (unsigned short)(sel << i);
  }
  tmp[l] = mybits;
  __syncthreads();
  if (l < 16) {
    mrow[l] = (unsigned long long)tmp[4 * l] | ((unsigned long long)tmp[4 * l + 1] << 16) |
              ((unsigned long long)tmp[4 * l + 2] << 32) | ((unsigned long long)tmp[4 * l + 3] << 48);
  }
}

__global__ __launch_bounds__(64) void k_route(const float* __restrict__ hs2, const float* __restrict__ wg,
                                              int* __restrict__ cnt, int* __restrict__ toki,
                                              float* __restrict__ tokw) {
  int t = blockIdx.x; int l = threadIdx.x;
  float acc[8] = {};
  for (int d = l; d < kD; d += 64) {
    float hv = hs2[(size_t)t * kD + d];
    const float* wr = wg + (size_t)d * 8;
#pragma unroll
    for (int e = 0; e < 8; e++) acc[e] += hv * wr[e];
  }
#pragma unroll
  for (int e = 0; e < 8; e++) acc[e] = wsum(acc[e]);
  if (l == 0) {
    float g[8];
#pragma unroll
    for (int e = 0; e < 8; e++) g[e] = 1.0f / (1.0f + expf(-acc[e]));
    int i0 = 0;
    for (int e = 1; e < 8; e++) if (g[e] > g[i0]) i0 = e;
    int i1 = (i0 == 0) ? 1 : 0;
    for (int e = 0; e < 8; e++) if (e != i0 && g[e] > g[i1]) i1 = e;
    float ssum = g[i0] + g[i1];
    float w0 = g[i0] / ssum * 2.5f, w1 = g[i1] / ssum * 2.5f;
    int s0 = atomicAdd(&cnt[i0], 1); toki[i0 * kT + s0] = t; tokw[i0 * kT + s0] = w0;
    int s1 = atomicAdd(&cnt[i1], 1); toki[i1 * kT + s1] = t; tokw[i1 * kT + s1] = w1;
  }
}

// ---------------- launch ----------------
extern "C" void kernel_launch(void* const* d_in, const int* in_sizes, int n_in,
                              void* d_out, int out_size, void* d_ws, size_t ws_size,
                              hipStream_t stream) {
  (void)in_sizes; (void)n_in; (void)out_size; (void)ws_size;
  const int*   positions  = (const int*)d_in[0];
  const float* hidden     = (const float*)d_in[1];
  const float* residual   = (const float*)d_in[2];
  const float* input_ln_w = (const float*)d_in[3];
  const float* post_ln_w  = (const float*)d_in[4];
  const float* w_qkv_a    = (const float*)d_in[5];
  const float* q_a_ln_w   = (const float*)d_in[6];
  const float* w_q_b      = (const float*)d_in[7];
  const float* kv_a_ln_w  = (const float*)d_in[8];
  const float* w_kv_b     = (const float*)d_in[9];
  const float* w_o        = (const float*)d_in[10];
  const float* w_idx_q_b  = (const float*)d_in[11];
  const float* w_idx_k    = (const float*)d_in[12];
  const float* idx_k_ln_w = (const float*)d_in[13];
  const float* idx_k_ln_b = (const float*)d_in[14];
  const float* w_idx_w    = (const float*)d_in[15];
  const float* w_gate     = (const float*)d_in[16];
  const float* w_moe_gate = (const float*)d_in[17];
  const float* w_moe_up   = (const float*)d_in[18];
  const float* w_moe_down = (const float*)d_in[19];
  const float* w_sh_gate  = (const float*)d_in[20];
  const float* w_sh_up    = (const float*)d_in[21];
  const float* w_sh_down  = (const float*)d_in[22];

  float* out0 = (float*)d_out;
  float* out1 = out0 + (size_t)kT * kD;

  char* W = (char*)d_ws;
  size_t off = 0;
  auto alloc = [&](size_t bytes) { char* p = W + off; off += (bytes + 255) & ~(size_t)255; return p; };
  // f32 buffers
  float* resid   = (float*)alloc((size_t)kT * kD * 4);
  float* hs      = (float*)alloc((size_t)kT * kD * 4);
  float* qkv     = (float*)alloc((size_t)kT * kQKV_N * 4);
  float* qb      = (float*)alloc((size_t)kT * kH * kQKD * 4);
  float* kvb     = (float*)alloc((size_t)kT * kH * 256 * 4);
  float* iqb     = (float*)alloc((size_t)kT * kIH * kID * 4);
  float* ikraw   = (float*)alloc((size_t)kT * kID * 4);
  float* ikb     = (float*)alloc((size_t)kT * kID * 4);
  float* iksc    = (float*)alloc(kT * 4);
  float* iqsc    = (float*)alloc((size_t)kT * kIH * 4);
  float* iwraw   = (float*)alloc((size_t)kT * kIH * 4);
  float* iwb     = (float*)alloc((size_t)kT * kIH * 4);
  float* kpe     = (float*)alloc((size_t)kT * kROPE * 4);
  float* scoresb = (float*)alloc((size_t)kT * kT * 4);
  float* hs2     = (float*)alloc((size_t)kT * kD * 4);
  unsigned long long* mbits = (unsigned long long*)alloc((size_t)kT * 16 * 8);
  float* tokw    = (float*)alloc((size_t)kE * kT * 4);
  int*   toki    = (int*)alloc((size_t)kE * kT * 4);
  int*   cnt     = (int*)alloc(64);
  // bf16 activations
  u16* hs_h   = (u16*)alloc((size_t)kT * kD * 2);
  u16* hs_l   = (u16*)alloc((size_t)kT * kD * 2);
  u16* qc_h   = (u16*)alloc((size_t)kT * kQL * 2);
  u16* qc_l   = (u16*)alloc((size_t)kT * kQL * 2);
  u16* kvc_h  = (u16*)alloc((size_t)kT * kKVL * 2);
  u16* o_bf   = (u16*)alloc((size_t)kT * kH * kVD * 2);
  u16* hs2_h  = (u16*)alloc((size_t)kT * kD * 2);
  u16* sg_bf  = (u16*)alloc((size_t)kT * kF * 2);
  u16* hmid_bf= (u16*)alloc((size_t)kE * kT * kF * 2);
  // bf16 transposed weights
  u16* qkvBT_h = (u16*)alloc((size_t)kQKV_NP * kD * 2);
  u16* qkvBT_l = (u16*)alloc((size_t)kQKV_NP * kD * 2);
  u16* qbBT    = (u16*)alloc((size_t)kH * kQKD * kQL * 2);
  u16* kvbBT   = (u16*)alloc((size_t)kH * 256 * kKVL * 2);
  u16* woBT    = (u16*)alloc((size_t)kD * kH * kVD * 2);
  u16* iqBT_h  = (u16*)alloc((size_t)kIH * kID * kQL * 2);
  u16* iqBT_l  = (u16*)alloc((size_t)kIH * kID * kQL * 2);
  u16* ikBT_h  = (u16*)alloc((size_t)kID * kD * 2);
  u16* ikBT_l  = (u16*)alloc((size_t)kID * kD * 2);
  u16* shgBT   = (u16*)alloc((size_t)kF * kD * 2);
  u16* shuBT   = (u16*)alloc((size_t)kF * kD * 2);
  u16* shdBT   = (u16*)alloc((size_t)kD * kF * 2);
  u16* moegBT  = (u16*)alloc((size_t)kE * kF * kD * 2);
  u16* moeuBT  = (u16*)alloc((size_t)kE * kF * kD * 2);
  u16* moedBT  = (u16*)alloc((size_t)kE * kD * kF * 2);

  // ---- weight prep (runs every launch; inputs are constant) ----
  { dim3 g(kQKV_NP / 32, kD / 32); k_transpose_w<<<g, 256, 0, stream>>>(w_qkv_a, qkvBT_h, qkvBT_l, kD, kQKV_N, kQKV_NP); }
  { dim3 g(kH * kQKD / 32, kQL / 32); k_transpose_w<<<g, 256, 0, stream>>>(w_q_b, qbBT, nullptr, kQL, kH * kQKD, kH * kQKD); }
  { dim3 g(kH * 256 / 32, kKVL / 32); k_transpose_w<<<g, 256, 0, stream>>>(w_kv_b, kvbBT, nullptr, kKVL, kH * 256, kH * 256); }
  { dim3 g(kD / 32, kH * kVD / 32); k_transpose_w<<<g, 256, 0, stream>>>(w_o, woBT, nullptr, kH * kVD, kD, kD); }
  { dim3 g(kIH * kID / 32, kQL / 32); k_transpose_w<<<g, 256, 0, stream>>>(w_idx_q_b, iqBT_h, iqBT_l, kQL, kIH * kID, kIH * kID); }
  { dim3 g(kID / 32, kD / 32); k_transpose_w<<<g, 256, 0, stream>>>(w_idx_k, ikBT_h, ikBT_l, kD, kID, kID); }
  { dim3 g(kF / 32, kD / 32); k_transpose_w<<<g, 256, 0, stream>>>(w_sh_gate, shgBT, nullptr, kD, kF, kF); }
  { dim3 g(kF / 32, kD / 32); k_transpose_w<<<g, 256, 0, stream>>>(w_sh_up, shuBT, nullptr, kD, kF, kF); }
  { dim3 g(kD / 32, kF / 32); k_transpose_w<<<g, 256, 0, stream>>>(w_sh_down, shdBT, nullptr, kF, kD, kD); }
  { dim3 g(kF / 32, kD / 32, kE); k_transpose_w<<<g, 256, 0, stream>>>(w_moe_gate, moegBT, nullptr, kD, kF, kF); }
  { dim3 g(kF / 32, kD / 32, kE); k_transpose_w<<<g, 256, 0, stream>>>(w_moe_up, moeuBT, nullptr, kD, kF, kF); }
  { dim3 g(kD / 32, kF / 32, kE); k_transpose_w<<<g, 256, 0, stream>>>(w_moe_down, moedBT, nullptr, kF, kD, kD); }

  // ---- forward ----
  k_add_rms<<<kT, 256, 0, stream>>>(hidden, residual, input_ln_w, resid, hs, hs_h, hs_l);
  { dim3 g(kQKV_NP / 128, kT / 128); k_gemm_split<<<g, 256, 0, stream>>>(hs_h, hs_l, qkvBT_h, qkvBT_l, qkv, kT, kQKV_N, kD); }
  k_rms_rows<<<kT, 256, 0, stream>>>(qkv, kQKV_N, 0, q_a_ln_w, nullptr, qc_h, qc_l, kQL);
  k_rms_rows<<<kT, 256, 0, stream>>>(qkv, kQKV_N, kQL, kv_a_ln_w, nullptr, kvc_h, nullptr, kKVL);
  { dim3 g(kH * kQKD / 128, kT / 128); k_gemm_bt<<<g, 256, 0, stream>>>(qc_h, qbBT, qb, nullptr, kT, kH * kQKD, kQL); }
  { dim3 g(kIH * kID / 128, kT / 128); k_gemm_split<<<g, 256, 0, stream>>>(qc_h, qc_l, iqBT_h, iqBT_l, iqb, kT, kIH * kID, kQL); }
  { dim3 g(kH * 256 / 128, kT / 128); k_gemm_bt<<<g, 256, 0, stream>>>(kvc_h, kvbBT, kvb, nullptr, kT, kH * 256, kKVL); }
  { dim3 g(kID / 128, kT / 128); k_gemm_split<<<g, 256, 0, stream>>>(hs_h, hs_l, ikBT_h, ikBT_l, ikraw, kT, kID, kD); }
  { dim3 g(1, kT / 64); k_gemm<<<g, 256, 0, stream>>>(hs, w_idx_w, iwraw, kT, kIH, kD, nullptr); }
  k_rope_q<<<kT, 256, 0, stream>>>(qb, positions);
  k_rope_iq<<<kT, 256, 0, stream>>>(iqb, positions);
  k_rope_kpe<<<kT, 64, 0, stream>>>(qkv, positions, kpe);
  k_quant_rows<<<kT * kIH, 64, 0, stream>>>(iqb, iqsc);
  k_ik_process<<<kT, 64, 0, stream>>>(ikraw, idx_k_ln_w, idx_k_ln_b, positions, ikb, iksc);
  k_iw<<<(kT * kIH + 255) / 256, 256, 0, stream>>>(iwraw, iqsc, iwb);
  k_scores<<<kT, 256, 0, stream>>>(iqb, ikb, iksc, iwb, scoresb);
  k_topk<<<kT, 64, 0, stream>>>(scoresb, mbits);
  { dim3 g(kT / 64, kH); k_attn_mfma<<<g, 256, 0, stream>>>(qb, kvb, kpe, mbits, o_bf); }
  { dim3 g(kD / 128, kT / 128); k_gemm_bt<<<g, 256, 0, stream>>>(o_bf, woBT, out1, resid, kT, kD, kH * kVD); }
  k_rms_rows<<<kT, 256, 0, stream>>>(out1, kD, 0, post_ln_w, hs2, hs2_h, nullptr, kD);
  hipMemsetAsync(cnt, 0, 8 * sizeof(int), stream);
  k_route<<<kT, 64, 0, stream>>>(hs2, w_gate, cnt, toki, tokw);
  { dim3 g(kF / 128, kT / 128, 1); k_dual_bt<<<g, 256, 0, stream>>>(hs2_h, shgBT, shuBT, sg_bf, nullptr, nullptr, kT, kF, kD); }
  { dim3 g(kD / 128, kT / 128); k_gemm_bt<<<g, 256, 0, stream>>>(sg_bf, shdBT, out0, nullptr, kT, kD, kF); }
  { dim3 g(kF / 128, kT / 128, kE); k_dual_bt<<<g, 256, 0, stream>>>(hs2_h, moegBT, moeuBT, hmid_bf, toki, cnt, kT, kF, kD); }
  { dim3 g(kD / 128, kT / 128, kE); k_down_bt<<<g, 256, 0, stream>>>(hmid_bf, moedBT, toki, tokw, cnt, out0); }
}